// Round 1
// baseline (6909.931 us; speedup 1.0000x reference)
//
#include <hip/hip_runtime.h>

#define HD 100
#define NF 16
#define EF 8
#define NN 50000
#define NE 400000

__device__ __forceinline__ float frelu(float v) { return v > 0.f ? v : 0.f; }

__global__ __launch_bounds__(256) void k_node_embed(const float* __restrict__ x,
    const float* __restrict__ w, const float* __restrict__ b, float* __restrict__ h) {
  int t = blockIdx.x * 256 + threadIdx.x;
  int n = t / HD, o = t % HD;
  if (n >= NN) return;
  float acc = b[o];
  #pragma unroll
  for (int k = 0; k < NF; ++k) acc = fmaf(x[n * NF + k], w[k * HD + o], acc);
  h[n * HD + o] = acc;
}

__global__ __launch_bounds__(256) void k_edge_embed(const float* __restrict__ ea,
    const float* __restrict__ w, const float* __restrict__ b, float* __restrict__ e) {
  int t = blockIdx.x * 256 + threadIdx.x;
  int n = t / HD, o = t % HD;
  if (n >= NE) return;
  float acc = b[o];
  #pragma unroll
  for (int k = 0; k < EF; ++k) acc = fmaf(ea[n * EF + k], w[k * HD + o], acc);
  e[n * HD + o] = acc;
}

__global__ __launch_bounds__(256) void k_scatter(const float* __restrict__ h,
    const float* __restrict__ e, const int* __restrict__ src, const int* __restrict__ dst,
    float* __restrict__ agg) {
  int t = blockIdx.x * 256 + threadIdx.x;
  int ei = t / HD, o = t % HD;
  if (ei >= NE) return;
  float v = h[src[ei] * HD + o] + e[ei * HD + o];
  if (v > 0.f) atomicAdd(&agg[dst[ei] * HD + o], v);
}

// 64 nodes per block; z=h+agg; t=relu(z@w1+b1); z2=t@w2+b2; h=(h+relu(bn(z2)))*0.5
__global__ __launch_bounds__(256) void k_node_update(float* __restrict__ h,
    const float* __restrict__ agg,
    const float* __restrict__ w1, const float* __restrict__ b1,
    const float* __restrict__ w2, const float* __restrict__ b2,
    const float* __restrict__ gamma, const float* __restrict__ beta) {
  __shared__ float zs[64 * 101];
  __shared__ float ts[64 * 101];
  int tid = threadIdx.x;
  int base = blockIdx.x * 64;
  for (int idx = tid; idx < 64 * HD; idx += 256) {
    int n = idx / HD, k = idx % HD;
    int gn = base + n; int cn = gn < NN ? gn : NN - 1;
    zs[n * 101 + k] = h[cn * HD + k] + agg[cn * HD + k];
  }
  __syncthreads();
  int el = tid & 63, o0 = (tid >> 6) * 25;
  float acc[25];
  #pragma unroll
  for (int j = 0; j < 25; ++j) acc[j] = b1[o0 + j];
  for (int k = 0; k < HD; ++k) {
    float a = zs[el * 101 + k];
    #pragma unroll
    for (int j = 0; j < 25; ++j) acc[j] = fmaf(a, w1[k * HD + o0 + j], acc[j]);
  }
  #pragma unroll
  for (int j = 0; j < 25; ++j) ts[el * 101 + o0 + j] = frelu(acc[j]);
  __syncthreads();
  float acc2[25];
  #pragma unroll
  for (int j = 0; j < 25; ++j) acc2[j] = b2[o0 + j];
  for (int k = 0; k < HD; ++k) {
    float a = ts[el * 101 + k];
    #pragma unroll
    for (int j = 0; j < 25; ++j) acc2[j] = fmaf(a, w2[k * HD + o0 + j], acc2[j]);
  }
  int gn = base + el;
  if (gn < NN) {
    const float bninv = 0.99999500003749973f;  // 1/sqrt(1+1e-5)
    #pragma unroll
    for (int j = 0; j < 25; ++j) {
      int o = o0 + j;
      float bn = acc2[j] * (gamma[o] * bninv) + beta[o];
      h[gn * HD + o] = (h[gn * HD + o] + frelu(bn)) * 0.5f;
    }
  }
}

// 64 edges per block. ei=[h[src],h[dst],e] staged in LDS; e += (relu(ei@w1+b1)@w2+b2)*0.5
__global__ __launch_bounds__(256) void k_edge_update(const float* __restrict__ h,
    float* __restrict__ e, const int* __restrict__ src, const int* __restrict__ dst,
    const float* __restrict__ w1, const float* __restrict__ b1,
    const float* __restrict__ w2, const float* __restrict__ b2) {
  __shared__ float eis[64 * 301];
  __shared__ float ts[64 * 101];
  int tid = threadIdx.x;
  int base = blockIdx.x * 64;  // NE % 64 == 0
  for (int idx = tid; idx < 64 * 300; idx += 256) {
    int el = idx / 300, k = idx % 300;
    int ge = base + el;
    float v;
    if (k < 100) v = h[src[ge] * HD + k];
    else if (k < 200) v = h[dst[ge] * HD + (k - 100)];
    else v = e[ge * HD + (k - 200)];
    eis[el * 301 + k] = v;
  }
  __syncthreads();
  int el = tid & 63, o0 = (tid >> 6) * 25;
  float acc[25];
  #pragma unroll
  for (int j = 0; j < 25; ++j) acc[j] = b1[o0 + j];
  for (int k = 0; k < 300; ++k) {
    float a = eis[el * 301 + k];
    #pragma unroll
    for (int j = 0; j < 25; ++j) acc[j] = fmaf(a, w1[k * HD + o0 + j], acc[j]);
  }
  #pragma unroll
  for (int j = 0; j < 25; ++j) ts[el * 101 + o0 + j] = frelu(acc[j]);
  __syncthreads();
  float acc2[25];
  #pragma unroll
  for (int j = 0; j < 25; ++j) acc2[j] = b2[o0 + j];
  for (int k = 0; k < HD; ++k) {
    float a = ts[el * 101 + k];
    #pragma unroll
    for (int j = 0; j < 25; ++j) acc2[j] = fmaf(a, w2[k * HD + o0 + j], acc2[j]);
  }
  #pragma unroll
  for (int j = 0; j < 25; ++j) {
    int p = el * 301 + 200 + o0 + j;
    eis[p] = eis[p] + acc2[j] * 0.5f;
  }
  __syncthreads();
  for (int idx = tid; idx < 64 * HD; idx += 256) {
    int el2 = idx / HD, o = idx % HD;
    e[(base + el2) * HD + o] = eis[el2 * 301 + 200 + o];
  }
}

// one thread per edge: xe=[h[s],h[d],e]; relu(xe@w1+b1) -> relu(@w2+b2) -> @w3+b3
__global__ __launch_bounds__(256) void k_final(const float* __restrict__ h,
    const float* __restrict__ e, const int* __restrict__ src, const int* __restrict__ dst,
    const float* __restrict__ w1, const float* __restrict__ b1,
    const float* __restrict__ w2, const float* __restrict__ b2,
    const float* __restrict__ w3, const float* __restrict__ b3,
    float* __restrict__ out) {
  int t = blockIdx.x * 256 + threadIdx.x;
  int ge = t < NE ? t : NE - 1;
  int s = src[ge], d = dst[ge];
  float o1[50];
  #pragma unroll
  for (int j = 0; j < 50; ++j) o1[j] = b1[j];
  for (int k = 0; k < 100; ++k) {
    float a = h[s * HD + k];
    #pragma unroll
    for (int j = 0; j < 50; ++j) o1[j] = fmaf(a, w1[k * 50 + j], o1[j]);
  }
  for (int k = 0; k < 100; ++k) {
    float a = h[d * HD + k];
    #pragma unroll
    for (int j = 0; j < 50; ++j) o1[j] = fmaf(a, w1[(100 + k) * 50 + j], o1[j]);
  }
  for (int k = 0; k < 100; ++k) {
    float a = e[ge * HD + k];
    #pragma unroll
    for (int j = 0; j < 50; ++j) o1[j] = fmaf(a, w1[(200 + k) * 50 + j], o1[j]);
  }
  #pragma unroll
  for (int j = 0; j < 50; ++j) o1[j] = frelu(o1[j]);
  float o2[25];
  #pragma unroll
  for (int j = 0; j < 25; ++j) o2[j] = b2[j];
  for (int k = 0; k < 50; ++k) {
    float a = o1[k];
    #pragma unroll
    for (int j = 0; j < 25; ++j) o2[j] = fmaf(a, w2[k * 25 + j], o2[j]);
  }
  float r = b3[0];
  #pragma unroll
  for (int j = 0; j < 25; ++j) r = fmaf(frelu(o2[j]), w3[j], r);
  if (t < NE) out[t] = r;
}

extern "C" void kernel_launch(void* const* d_in, const int* in_sizes, int n_in,
                              void* d_out, int out_size, void* d_ws, size_t ws_size,
                              hipStream_t stream) {
  (void)in_sizes; (void)n_in; (void)out_size; (void)ws_size;
  const float* x       = (const float*)d_in[0];
  const int*   eidx    = (const int*)  d_in[1];
  const float* eattr   = (const float*)d_in[2];
  const float* node_w  = (const float*)d_in[3];
  const float* node_b  = (const float*)d_in[4];
  const float* edge_w  = (const float*)d_in[5];
  const float* edge_b  = (const float*)d_in[6];
  const float* conv_w1 = (const float*)d_in[7];
  const float* conv_b1 = (const float*)d_in[8];
  const float* conv_w2 = (const float*)d_in[9];
  const float* conv_b2 = (const float*)d_in[10];
  const float* bn_g    = (const float*)d_in[11];
  const float* bn_b    = (const float*)d_in[12];
  const float* em_w1   = (const float*)d_in[13];
  const float* em_b1   = (const float*)d_in[14];
  const float* em_w2   = (const float*)d_in[15];
  const float* em_b2   = (const float*)d_in[16];
  const float* mlp_w1  = (const float*)d_in[17];
  const float* mlp_b1  = (const float*)d_in[18];
  const float* mlp_w2  = (const float*)d_in[19];
  const float* mlp_b2  = (const float*)d_in[20];
  const float* mlp_w3  = (const float*)d_in[21];
  const float* mlp_b3  = (const float*)d_in[22];

  const int* src = eidx;
  const int* dst = eidx + NE;

  float* h   = (float*)d_ws;                 // NN*HD = 5,000,000 floats
  float* agg = h + (size_t)NN * HD;          // 5,000,000 floats
  float* e   = agg + (size_t)NN * HD;        // NE*HD = 40,000,000 floats

  k_node_embed<<<(NN * HD + 255) / 256, 256, 0, stream>>>(x, node_w, node_b, h);
  k_edge_embed<<<(NE * HD + 255) / 256, 256, 0, stream>>>(eattr, edge_w, edge_b, e);

  for (int i = 0; i < 2; ++i) {
    hipMemsetAsync(agg, 0, (size_t)NN * HD * sizeof(float), stream);
    k_scatter<<<(NE * HD + 255) / 256, 256, 0, stream>>>(h, e, src, dst, agg);
    k_node_update<<<(NN + 63) / 64, 256, 0, stream>>>(
        h, agg, conv_w1 + i * HD * HD, conv_b1 + i * HD,
        conv_w2 + i * HD * HD, conv_b2 + i * HD, bn_g + i * HD, bn_b + i * HD);
    k_edge_update<<<NE / 64, 256, 0, stream>>>(
        h, e, src, dst, em_w1 + i * 3 * HD * HD, em_b1 + i * HD,
        em_w2 + i * HD * HD, em_b2 + i * HD);
  }

  k_final<<<(NE + 255) / 256, 256, 0, stream>>>(
      h, e, src, dst, mlp_w1, mlp_b1, mlp_w2, mlp_b2, mlp_w3, mlp_b3, (float*)d_out);
}

// Round 2
// 4418.225 us; speedup vs baseline: 1.5640x; 1.5640x over previous
//
#include <hip/hip_runtime.h>

#define HD 100
#define NF 16
#define EF 8
#define NN 50000
#define NE 400000

__device__ __forceinline__ float frelu(float v) { return v > 0.f ? v : 0.f; }

__global__ __launch_bounds__(256) void k_node_embed(const float* __restrict__ x,
    const float* __restrict__ w, const float* __restrict__ b, float* __restrict__ h) {
  int t = blockIdx.x * 256 + threadIdx.x;
  int n = t / HD, o = t % HD;
  if (n >= NN) return;
  float acc = b[o];
  #pragma unroll
  for (int k = 0; k < NF; ++k) acc = fmaf(x[n * NF + k], w[k * HD + o], acc);
  h[n * HD + o] = acc;
}

__global__ __launch_bounds__(256) void k_edge_embed(const float* __restrict__ ea,
    const float* __restrict__ w, const float* __restrict__ b, float* __restrict__ e) {
  int t = blockIdx.x * 256 + threadIdx.x;
  int n = t / HD, o = t % HD;
  if (n >= NE) return;
  float acc = b[o];
  #pragma unroll
  for (int k = 0; k < EF; ++k) acc = fmaf(ea[n * EF + k], w[k * HD + o], acc);
  e[n * HD + o] = acc;
}

// 25 threads per edge, 4 consecutive h-dims each (float4 loads)
__global__ __launch_bounds__(256) void k_scatter(const float* __restrict__ h,
    const float* __restrict__ e, const int* __restrict__ src, const int* __restrict__ dst,
    float* __restrict__ agg) {
  long long t = (long long)blockIdx.x * 256 + threadIdx.x;
  int ei = (int)(t / 25), q = (int)(t % 25) * 4;
  if (ei >= NE) return;
  int s = src[ei], d = dst[ei];
  float4 hv = *(const float4*)&h[s * HD + q];
  float4 ev = *(const float4*)&e[(size_t)ei * HD + q];
  float v0 = hv.x + ev.x, v1 = hv.y + ev.y, v2 = hv.z + ev.z, v3 = hv.w + ev.w;
  float* ap = &agg[(size_t)d * HD + q];
  if (v0 > 0.f) atomicAdd(ap + 0, v0);
  if (v1 > 0.f) atomicAdd(ap + 1, v1);
  if (v2 > 0.f) atomicAdd(ap + 2, v2);
  if (v3 > 0.f) atomicAdd(ap + 3, v3);
}

// 64 nodes per block; z=h+agg; t=relu(z@w1+b1); z2=t@w2+b2; h=(h+relu(bn(z2)))*0.5
// t-buffer aliased into zs (z region dead after GEMM1).
__global__ __launch_bounds__(256) void k_node_update(float* __restrict__ h,
    const float* __restrict__ agg,
    const float* __restrict__ w1, const float* __restrict__ b1,
    const float* __restrict__ w2, const float* __restrict__ b2,
    const float* __restrict__ gamma, const float* __restrict__ beta) {
  __shared__ float zs[64 * 101];
  int tid = threadIdx.x;
  int base = blockIdx.x * 64;
  for (int idx = tid; idx < 64 * HD; idx += 256) {
    int n = idx / HD, k = idx % HD;
    int gn = base + n; int cn = gn < NN ? gn : NN - 1;
    zs[n * 101 + k] = h[(size_t)cn * HD + k] + agg[(size_t)cn * HD + k];
  }
  __syncthreads();
  int el = tid & 63;
  int o0 = __builtin_amdgcn_readfirstlane((tid >> 6) * 25);
  float* row = &zs[el * 101];
  float acc[25];
  #pragma unroll
  for (int j = 0; j < 25; ++j) acc[j] = b1[o0 + j];
  for (int k = 0; k < HD; ++k) {
    float a = row[k];
    const float* wr = &w1[k * HD + o0];
    #pragma unroll
    for (int j = 0; j < 25; ++j) acc[j] = fmaf(a, wr[j], acc[j]);
  }
  __syncthreads();
  #pragma unroll
  for (int j = 0; j < 25; ++j) row[o0 + j] = frelu(acc[j]);
  __syncthreads();
  float acc2[25];
  #pragma unroll
  for (int j = 0; j < 25; ++j) acc2[j] = b2[o0 + j];
  for (int k = 0; k < HD; ++k) {
    float a = row[k];
    const float* wr = &w2[k * HD + o0];
    #pragma unroll
    for (int j = 0; j < 25; ++j) acc2[j] = fmaf(a, wr[j], acc2[j]);
  }
  int gn = base + el;
  if (gn < NN) {
    const float bninv = 0.99999500003749973f;  // 1/sqrt(1+1e-5)
    #pragma unroll
    for (int j = 0; j < 25; ++j) {
      int o = o0 + j;
      float bn = acc2[j] * (gamma[o] * bninv) + beta[o];
      h[(size_t)gn * HD + o] = (h[(size_t)gn * HD + o] + frelu(bn)) * 0.5f;
    }
  }
}

// 64 edges per block. ei=[h[src],h[dst],e] in LDS; e += (relu(ei@w1+b1)@w2+b2)*0.5
// t-buffer aliased into eis[el][0..99] (h[src] region dead after GEMM1).
__global__ __launch_bounds__(256) void k_edge_update(const float* __restrict__ h,
    float* __restrict__ e, const int* __restrict__ src, const int* __restrict__ dst,
    const float* __restrict__ w1, const float* __restrict__ b1,
    const float* __restrict__ w2, const float* __restrict__ b2) {
  __shared__ float eis[64 * 301];
  int tid = threadIdx.x;
  int base = blockIdx.x * 64;  // NE % 64 == 0
  for (int idx = tid; idx < 64 * 300; idx += 256) {
    int el = idx / 300, k = idx % 300;
    int ge = base + el;
    float v;
    if (k < 100) v = h[(size_t)src[ge] * HD + k];
    else if (k < 200) v = h[(size_t)dst[ge] * HD + (k - 100)];
    else v = e[(size_t)ge * HD + (k - 200)];
    eis[el * 301 + k] = v;
  }
  __syncthreads();
  int el = tid & 63;
  int o0 = __builtin_amdgcn_readfirstlane((tid >> 6) * 25);
  float* row = &eis[el * 301];
  float acc[25];
  #pragma unroll
  for (int j = 0; j < 25; ++j) acc[j] = b1[o0 + j];
  for (int k = 0; k < 300; ++k) {
    float a = row[k];
    const float* wr = &w1[k * HD + o0];
    #pragma unroll
    for (int j = 0; j < 25; ++j) acc[j] = fmaf(a, wr[j], acc[j]);
  }
  __syncthreads();          // all GEMM1 reads of eis done
  #pragma unroll
  for (int j = 0; j < 25; ++j) row[o0 + j] = frelu(acc[j]);   // t into dead h[src] region
  __syncthreads();
  float acc2[25];
  #pragma unroll
  for (int j = 0; j < 25; ++j) acc2[j] = b2[o0 + j];
  for (int k = 0; k < HD; ++k) {
    float a = row[k];
    const float* wr = &w2[k * HD + o0];
    #pragma unroll
    for (int j = 0; j < 25; ++j) acc2[j] = fmaf(a, wr[j], acc2[j]);
  }
  #pragma unroll
  for (int j = 0; j < 25; ++j) {
    int p = 200 + o0 + j;
    row[p] = row[p] + acc2[j] * 0.5f;   // own slice only, no cross-thread hazard
  }
  __syncthreads();
  for (int idx = tid; idx < 64 * HD; idx += 256) {
    int el2 = idx / HD, o = idx % HD;
    e[(size_t)(base + el2) * HD + o] = eis[el2 * 301 + 200 + o];
  }
}

// one thread per edge: xe=[h[s],h[d],e]; relu(xe@w1+b1) -> relu(@w2+b2) -> @w3+b3
__global__ __launch_bounds__(256) void k_final(const float* __restrict__ h,
    const float* __restrict__ e, const int* __restrict__ src, const int* __restrict__ dst,
    const float* __restrict__ w1, const float* __restrict__ b1,
    const float* __restrict__ w2, const float* __restrict__ b2,
    const float* __restrict__ w3, const float* __restrict__ b3,
    float* __restrict__ out) {
  int t = blockIdx.x * 256 + threadIdx.x;
  int ge = t < NE ? t : NE - 1;
  int s = src[ge], d = dst[ge];
  float o1[50];
  #pragma unroll
  for (int j = 0; j < 50; ++j) o1[j] = b1[j];
  for (int k = 0; k < 100; ++k) {
    float a = h[(size_t)s * HD + k];
    #pragma unroll
    for (int j = 0; j < 50; ++j) o1[j] = fmaf(a, w1[k * 50 + j], o1[j]);
  }
  for (int k = 0; k < 100; ++k) {
    float a = h[(size_t)d * HD + k];
    #pragma unroll
    for (int j = 0; j < 50; ++j) o1[j] = fmaf(a, w1[(100 + k) * 50 + j], o1[j]);
  }
  for (int k = 0; k < 100; ++k) {
    float a = e[(size_t)ge * HD + k];
    #pragma unroll
    for (int j = 0; j < 50; ++j) o1[j] = fmaf(a, w1[(200 + k) * 50 + j], o1[j]);
  }
  #pragma unroll
  for (int j = 0; j < 50; ++j) o1[j] = frelu(o1[j]);
  float o2[25];
  #pragma unroll
  for (int j = 0; j < 25; ++j) o2[j] = b2[j];
  for (int k = 0; k < 50; ++k) {
    float a = o1[k];
    #pragma unroll
    for (int j = 0; j < 25; ++j) o2[j] = fmaf(a, w2[k * 25 + j], o2[j]);
  }
  float r = b3[0];
  #pragma unroll
  for (int j = 0; j < 25; ++j) r = fmaf(frelu(o2[j]), w3[j], r);
  if (t < NE) out[t] = r;
}

extern "C" void kernel_launch(void* const* d_in, const int* in_sizes, int n_in,
                              void* d_out, int out_size, void* d_ws, size_t ws_size,
                              hipStream_t stream) {
  (void)in_sizes; (void)n_in; (void)out_size; (void)ws_size;
  const float* x       = (const float*)d_in[0];
  const int*   eidx    = (const int*)  d_in[1];
  const float* eattr   = (const float*)d_in[2];
  const float* node_w  = (const float*)d_in[3];
  const float* node_b  = (const float*)d_in[4];
  const float* edge_w  = (const float*)d_in[5];
  const float* edge_b  = (const float*)d_in[6];
  const float* conv_w1 = (const float*)d_in[7];
  const float* conv_b1 = (const float*)d_in[8];
  const float* conv_w2 = (const float*)d_in[9];
  const float* conv_b2 = (const float*)d_in[10];
  const float* bn_g    = (const float*)d_in[11];
  const float* bn_b    = (const float*)d_in[12];
  const float* em_w1   = (const float*)d_in[13];
  const float* em_b1   = (const float*)d_in[14];
  const float* em_w2   = (const float*)d_in[15];
  const float* em_b2   = (const float*)d_in[16];
  const float* mlp_w1  = (const float*)d_in[17];
  const float* mlp_b1  = (const float*)d_in[18];
  const float* mlp_w2  = (const float*)d_in[19];
  const float* mlp_b2  = (const float*)d_in[20];
  const float* mlp_w3  = (const float*)d_in[21];
  const float* mlp_b3  = (const float*)d_in[22];

  const int* src = eidx;
  const int* dst = eidx + NE;

  float* h   = (float*)d_ws;                 // NN*HD floats
  float* agg = h + (size_t)NN * HD;
  float* e   = agg + (size_t)NN * HD;        // NE*HD floats

  k_node_embed<<<(NN * HD + 255) / 256, 256, 0, stream>>>(x, node_w, node_b, h);
  k_edge_embed<<<(NE * HD + 255) / 256, 256, 0, stream>>>(eattr, edge_w, edge_b, e);

  for (int i = 0; i < 2; ++i) {
    hipMemsetAsync(agg, 0, (size_t)NN * HD * sizeof(float), stream);
    long long sth = (long long)NE * 25;
    k_scatter<<<(unsigned)((sth + 255) / 256), 256, 0, stream>>>(h, e, src, dst, agg);
    k_node_update<<<(NN + 63) / 64, 256, 0, stream>>>(
        h, agg, conv_w1 + i * HD * HD, conv_b1 + i * HD,
        conv_w2 + i * HD * HD, conv_b2 + i * HD, bn_g + i * HD, bn_b + i * HD);
    k_edge_update<<<NE / 64, 256, 0, stream>>>(
        h, e, src, dst, em_w1 + i * 3 * HD * HD, em_b1 + i * HD,
        em_w2 + i * HD * HD, em_b2 + i * HD);
  }

  k_final<<<(NE + 255) / 256, 256, 0, stream>>>(
      h, e, src, dst, mlp_w1, mlp_b1, mlp_w2, mlp_b2, mlp_w3, mlp_b3, (float*)d_out);
}

// Round 4
// 2340.594 us; speedup vs baseline: 2.9522x; 1.8877x over previous
//
#include <hip/hip_runtime.h>

#define HD 100
#define NF 16
#define EF 8
#define NN 50000
#define NE 400000

typedef __attribute__((ext_vector_type(8))) short bf16x8;
typedef __attribute__((ext_vector_type(4))) float f32x4;

__device__ __forceinline__ float frelu(float v) { return v > 0.f ? v : 0.f; }
__device__ __forceinline__ unsigned short f2bf(float f) {
  unsigned int u = __float_as_uint(f);
  unsigned int r = (u + 0x7FFF + ((u >> 16) & 1)) >> 16;   // RNE
  return (unsigned short)r;
}
// XOR-swizzle: spread bank-aligned rows across 16B slots (G4 / T2)
__device__ __forceinline__ int SWZ(int row, int byte) { return byte ^ ((row & 7) << 4); }

// ---------------- weight pre-pack: W[K][N] fp32 -> frag-linear bf16 ----------------
// out[((ks*NT+nt)*64+lane)*8+j] = bf16(W[ks*32+(lane>>4)*8+j][nt*16+(lane&15)]) or 0
__global__ __launch_bounds__(256) void k_pack(const float* __restrict__ W,
    unsigned short* __restrict__ out, int K, int N, int KS, int NT) {
  int t = blockIdx.x * 256 + threadIdx.x;
  if (t >= KS * NT * 64) return;
  int lane = t & 63, nt = (t >> 6) % NT, ks = (t >> 6) / NT;
  int kb = ks * 32 + (lane >> 4) * 8, n = nt * 16 + (lane & 15);
  unsigned short v[8];
  #pragma unroll
  for (int j = 0; j < 8; ++j) {
    int k = kb + j;
    float f = (k < K && n < N) ? W[(size_t)k * N + n] : 0.f;
    v[j] = f2bf(f);
  }
  uint4 o4;
  o4.x = (unsigned)v[0] | ((unsigned)v[1] << 16);
  o4.y = (unsigned)v[2] | ((unsigned)v[3] << 16);
  o4.z = (unsigned)v[4] | ((unsigned)v[5] << 16);
  o4.w = (unsigned)v[6] | ((unsigned)v[7] << 16);
  *(uint4*)&out[(size_t)t * 8] = o4;
}

__global__ __launch_bounds__(256) void k_node_embed(const float* __restrict__ x,
    const float* __restrict__ w, const float* __restrict__ b, float* __restrict__ h) {
  int t = blockIdx.x * 256 + threadIdx.x;
  int n = t / HD, o = t % HD;
  if (n >= NN) return;
  float acc = b[o];
  #pragma unroll
  for (int k = 0; k < NF; ++k) acc = fmaf(x[n * NF + k], w[k * HD + o], acc);
  h[(size_t)n * HD + o] = acc;
}

__global__ __launch_bounds__(256) void k_edge_embed(const float* __restrict__ ea,
    const float* __restrict__ w, const float* __restrict__ b, float* __restrict__ e) {
  int t = blockIdx.x * 256 + threadIdx.x;
  int n = t / HD, o = t % HD;
  if (n >= NE) return;
  float acc = b[o];
  #pragma unroll
  for (int k = 0; k < EF; ++k) acc = fmaf(ea[n * EF + k], w[k * HD + o], acc);
  e[(size_t)n * HD + o] = acc;
}

// 25 threads per edge, 4 consecutive dims each (fp32 path: accuracy-critical)
__global__ __launch_bounds__(256) void k_scatter(const float* __restrict__ h,
    const float* __restrict__ e, const int* __restrict__ src, const int* __restrict__ dst,
    float* __restrict__ agg) {
  long long t = (long long)blockIdx.x * 256 + threadIdx.x;
  int ei = (int)(t / 25), q = (int)(t % 25) * 4;
  if (ei >= NE) return;
  int s = src[ei], d = dst[ei];
  float4 hv = *(const float4*)&h[(size_t)s * HD + q];
  float4 ev = *(const float4*)&e[(size_t)ei * HD + q];
  float v0 = hv.x + ev.x, v1 = hv.y + ev.y, v2 = hv.z + ev.z, v3 = hv.w + ev.w;
  float* ap = &agg[(size_t)d * HD + q];
  if (v0 > 0.f) atomicAdd(ap + 0, v0);
  if (v1 > 0.f) atomicAdd(ap + 1, v1);
  if (v2 > 0.f) atomicAdd(ap + 2, v2);
  if (v3 > 0.f) atomicAdd(ap + 3, v3);
}

// fp32 node update (accuracy-critical path)
__global__ __launch_bounds__(256) void k_node_update(float* __restrict__ h,
    const float* __restrict__ agg,
    const float* __restrict__ w1, const float* __restrict__ b1,
    const float* __restrict__ w2, const float* __restrict__ b2,
    const float* __restrict__ gamma, const float* __restrict__ beta) {
  __shared__ float zs[64 * 101];
  int tid = threadIdx.x;
  int base = blockIdx.x * 64;
  for (int idx = tid; idx < 64 * HD; idx += 256) {
    int n = idx / HD, k = idx % HD;
    int gn = base + n; int cn = gn < NN ? gn : NN - 1;
    zs[n * 101 + k] = h[(size_t)cn * HD + k] + agg[(size_t)cn * HD + k];
  }
  __syncthreads();
  int el = tid & 63;
  int o0 = __builtin_amdgcn_readfirstlane((tid >> 6) * 25);
  float* row = &zs[el * 101];
  float acc[25];
  #pragma unroll
  for (int j = 0; j < 25; ++j) acc[j] = b1[o0 + j];
  for (int k = 0; k < HD; ++k) {
    float a = row[k];
    const float* wr = &w1[k * HD + o0];
    #pragma unroll
    for (int j = 0; j < 25; ++j) acc[j] = fmaf(a, wr[j], acc[j]);
  }
  __syncthreads();
  #pragma unroll
  for (int j = 0; j < 25; ++j) row[o0 + j] = frelu(acc[j]);
  __syncthreads();
  float acc2[25];
  #pragma unroll
  for (int j = 0; j < 25; ++j) acc2[j] = b2[o0 + j];
  for (int k = 0; k < HD; ++k) {
    float a = row[k];
    const float* wr = &w2[k * HD + o0];
    #pragma unroll
    for (int j = 0; j < 25; ++j) acc2[j] = fmaf(a, wr[j], acc2[j]);
  }
  int gn = base + el;
  if (gn < NN) {
    const float bninv = 0.99999500003749973f;  // 1/sqrt(1+1e-5)
    #pragma unroll
    for (int j = 0; j < 25; ++j) {
      int o = o0 + j;
      float bn = acc2[j] * (gamma[o] * bninv) + beta[o];
      h[(size_t)gn * HD + o] = (h[(size_t)gn * HD + o] + frelu(bn)) * 0.5f;
    }
  }
}

// ---------------- MFMA edge update: 64 edges/block, 4 waves ----------------
// GEMM1: [64x320]bf16 @ W1p[320x112] ; GEMM2: [64x128]bf16 @ W2p[128x112]
// e += 0.5*(GEMM2 + b2)  (fp32 master). A staged from fp32 masters, cvt in-kernel.
__global__ __launch_bounds__(256) void k_edge_mfma(
    const float* __restrict__ h, float* __restrict__ e,
    const int* __restrict__ src, const int* __restrict__ dst,
    const unsigned short* __restrict__ w1p, const float* __restrict__ b1,
    const unsigned short* __restrict__ w2p, const float* __restrict__ b2) {
  __shared__ __align__(16) char lds[55296];
  char* A1 = lds;                 // 64 rows x 640B (A2 phase: 64 x 256B)
  char* WBa = lds + 40960;        // 7168B
  char* WBb = lds + 48128;        // 7168B
  int tid = threadIdx.x;
  int base = blockIdx.x * 64;
  // stage A1 = bf16([h_src | h_dst | e]) swizzled; cols 300..319 zero
  for (int idx = tid; idx < 64 * 75; idx += 256) {
    int row = idx / 75, c4 = idx % 75;
    int ge = base + row;
    const float* sp;
    if (c4 < 25)      sp = &h[(size_t)src[ge] * HD + c4 * 4];
    else if (c4 < 50) sp = &h[(size_t)dst[ge] * HD + (c4 - 25) * 4];
    else              sp = &e[(size_t)ge * HD + (c4 - 50) * 4];
    float4 f = *(const float4*)sp;
    uint2 o;
    o.x = (unsigned)f2bf(f.x) | ((unsigned)f2bf(f.y) << 16);
    o.y = (unsigned)f2bf(f.z) | ((unsigned)f2bf(f.w) << 16);
    *(uint2*)(A1 + SWZ(row, row * 640 + c4 * 8)) = o;
  }
  for (int idx = tid; idx < 64 * 5; idx += 256) {
    int row = idx / 5, j = idx % 5;
    uint2 z; z.x = 0u; z.y = 0u;
    *(uint2*)(A1 + SWZ(row, row * 640 + 600 + j * 8)) = z;
  }
  // stage W1 panel 0
  for (int c = tid; c < 448; c += 256)
    *(uint4*)(WBa + c * 16) = ((const uint4*)w1p)[c];
  __syncthreads();

  int lane = tid & 63, w = tid >> 6;
  int l15 = lane & 15, lq = lane >> 4;
  f32x4 zero = {0.f, 0.f, 0.f, 0.f};
  f32x4 acc[7];
  #pragma unroll
  for (int nt = 0; nt < 7; ++nt) acc[nt] = zero;

  for (int ks = 0; ks < 10; ++ks) {
    char* rb = (ks & 1) ? WBb : WBa;
    char* wb = (ks & 1) ? WBa : WBb;
    uint4 st0, st1;
    if (ks < 9) {
      const uint4* wp = (const uint4*)w1p + (size_t)(ks + 1) * 448;
      st0 = wp[tid];
      if (tid < 192) st1 = wp[256 + tid];
    }
    int arow = w * 16 + l15;
    bf16x8 a = *(const bf16x8*)(A1 + SWZ(arow, arow * 640 + (ks * 32 + lq * 8) * 2));
    #pragma unroll
    for (int nt = 0; nt < 7; ++nt) {
      bf16x8 b = *(const bf16x8*)(rb + (nt * 64 + lane) * 16);
      acc[nt] = __builtin_amdgcn_mfma_f32_16x16x32_bf16(a, b, acc[nt], 0, 0, 0);
    }
    if (ks < 9) {
      *(uint4*)(wb + tid * 16) = st0;
      if (tid < 192) *(uint4*)(wb + (256 + tid) * 16) = st1;
    }
    __syncthreads();
  }

  // epilogue1: relu(C1+b1) -> bf16 A2 [64][128] (stride 256B) in A1 region
  #pragma unroll
  for (int nt = 0; nt < 7; ++nt) {
    int o = nt * 16 + l15;
    float bias = (o < HD) ? b1[o] : 0.f;
    #pragma unroll
    for (int i = 0; i < 4; ++i) {
      int r = w * 16 + lq * 4 + i;
      float v = acc[nt][i] + bias;
      v = (o < HD) ? frelu(v) : 0.f;
      *(unsigned short*)(A1 + SWZ(r, r * 256 + o * 2)) = f2bf(v);
    }
  }
  // zero A2 cols 112..127
  for (int idx = tid; idx < 64 * 8; idx += 256) {
    int r = idx / 8, c = idx % 8;
    *(unsigned int*)(A1 + SWZ(r, r * 256 + 224 + c * 4)) = 0;
  }
  // stage W2 panel 0
  for (int c = tid; c < 448; c += 256)
    *(uint4*)(WBa + c * 16) = ((const uint4*)w2p)[c];
  __syncthreads();

  f32x4 acc2[7];
  #pragma unroll
  for (int nt = 0; nt < 7; ++nt) acc2[nt] = zero;
  for (int ks = 0; ks < 4; ++ks) {
    char* rb = (ks & 1) ? WBb : WBa;
    char* wb = (ks & 1) ? WBa : WBb;
    uint4 st0, st1;
    if (ks < 3) {
      const uint4* wp = (const uint4*)w2p + (size_t)(ks + 1) * 448;
      st0 = wp[tid];
      if (tid < 192) st1 = wp[256 + tid];
    }
    int arow = w * 16 + l15;
    bf16x8 a = *(const bf16x8*)(A1 + SWZ(arow, arow * 256 + (ks * 32 + lq * 8) * 2));
    #pragma unroll
    for (int nt = 0; nt < 7; ++nt) {
      bf16x8 b = *(const bf16x8*)(rb + (nt * 64 + lane) * 16);
      acc2[nt] = __builtin_amdgcn_mfma_f32_16x16x32_bf16(a, b, acc2[nt], 0, 0, 0);
    }
    if (ks < 3) {
      *(uint4*)(wb + tid * 16) = st0;
      if (tid < 192) *(uint4*)(wb + (256 + tid) * 16) = st1;
    }
    __syncthreads();
  }
  // epilogue2: e += 0.5*(C2+b2)
  #pragma unroll
  for (int nt = 0; nt < 7; ++nt) {
    int o = nt * 16 + l15;
    if (o < HD) {
      float bias = b2[o];
      #pragma unroll
      for (int i = 0; i < 4; ++i) {
        int r = w * 16 + lq * 4 + i;
        size_t p = (size_t)(base + r) * HD + o;
        e[p] = e[p] + 0.5f * (acc2[nt][i] + bias);
      }
    }
  }
}

// ---------------- MFMA final MLP: 64 edges/block ----------------
// GEMM1: [64x320]bf16 @ Wf[320x64] ; then fp32 layers 50->25->1 from LDS
__global__ __launch_bounds__(256) void k_final_mfma(
    const float* __restrict__ h, const float* __restrict__ e,
    const int* __restrict__ src, const int* __restrict__ dst,
    const unsigned short* __restrict__ wf1p, const float* __restrict__ b1,
    const float* __restrict__ w2, const float* __restrict__ b2,
    const float* __restrict__ w3, const float* __restrict__ b3,
    float* __restrict__ out) {
  __shared__ __align__(16) char lds[55296];
  char* A1 = lds;                 // 64 x 640B ; phase2: t fp32 64 x 208B
  char* WBa = lds + 40960;        // 4096B
  char* WBb = lds + 45056;        // 4096B
  float* W2s = (float*)(lds + 49152);   // 1250 floats
  float* b2s = (float*)(lds + 54152);   // 25
  float* W3s = (float*)(lds + 54252);   // 25
  float* b3s = (float*)(lds + 54352);   // 1
  int tid = threadIdx.x;
  int base = blockIdx.x * 64;
  for (int idx = tid; idx < 64 * 75; idx += 256) {
    int row = idx / 75, c4 = idx % 75;
    int ge = base + row;
    const float* sp;
    if (c4 < 25)      sp = &h[(size_t)src[ge] * HD + c4 * 4];
    else if (c4 < 50) sp = &h[(size_t)dst[ge] * HD + (c4 - 25) * 4];
    else              sp = &e[(size_t)ge * HD + (c4 - 50) * 4];
    float4 f = *(const float4*)sp;
    uint2 o;
    o.x = (unsigned)f2bf(f.x) | ((unsigned)f2bf(f.y) << 16);
    o.y = (unsigned)f2bf(f.z) | ((unsigned)f2bf(f.w) << 16);
    *(uint2*)(A1 + SWZ(row, row * 640 + c4 * 8)) = o;
  }
  for (int idx = tid; idx < 64 * 5; idx += 256) {
    int row = idx / 5, j = idx % 5;
    uint2 z; z.x = 0u; z.y = 0u;
    *(uint2*)(A1 + SWZ(row, row * 640 + 600 + j * 8)) = z;
  }
  for (int c = tid; c < 256; c += 256) *(uint4*)(WBa + c * 16) = ((const uint4*)wf1p)[c];
  for (int c = tid; c < 1250; c += 256) W2s[c] = w2[c];
  if (tid < 25) { b2s[tid] = b2[tid]; W3s[tid] = w3[tid]; }
  if (tid == 0) b3s[0] = b3[0];
  __syncthreads();

  int lane = tid & 63, w = tid >> 6;
  int l15 = lane & 15, lq = lane >> 4;
  f32x4 zero = {0.f, 0.f, 0.f, 0.f};
  f32x4 acc[4];
  #pragma unroll
  for (int nt = 0; nt < 4; ++nt) acc[nt] = zero;
  for (int ks = 0; ks < 10; ++ks) {
    char* rb = (ks & 1) ? WBb : WBa;
    char* wb = (ks & 1) ? WBa : WBb;
    uint4 st0;
    if (ks < 9) st0 = ((const uint4*)wf1p)[(size_t)(ks + 1) * 256 + tid];
    int arow = w * 16 + l15;
    bf16x8 a = *(const bf16x8*)(A1 + SWZ(arow, arow * 640 + (ks * 32 + lq * 8) * 2));
    #pragma unroll
    for (int nt = 0; nt < 4; ++nt) {
      bf16x8 b = *(const bf16x8*)(rb + (nt * 64 + lane) * 16);
      acc[nt] = __builtin_amdgcn_mfma_f32_16x16x32_bf16(a, b, acc[nt], 0, 0, 0);
    }
    if (ks < 9) *(uint4*)(wb + tid * 16) = st0;
    __syncthreads();
  }
  // t = relu(C1+b1) fp32 [64][52] in A1 region
  #pragma unroll
  for (int nt = 0; nt < 4; ++nt) {
    int o = nt * 16 + l15;
    if (o < 50) {
      float bias = b1[o];
      #pragma unroll
      for (int i = 0; i < 4; ++i) {
        int r = w * 16 + lq * 4 + i;
        *(float*)(A1 + r * 208 + o * 4) = frelu(acc[nt][i] + bias);
      }
    }
  }
  __syncthreads();
  // layers 2+3: 4 threads per edge
  int el = tid >> 2, q = tid & 3;
  const float* trow = (const float*)(A1 + el * 208);
  float s[7];
  {
    int i = 0;
    #pragma unroll
    for (int j0 = 0; j0 < 25; j0 += 4) { if (j0 + q < 25) s[i++] = b2s[j0 + q]; }
  }
  for (int k = 0; k < 50; ++k) {
    float tv = trow[k];
    int i = 0;
    #pragma unroll
    for (int j0 = 0; j0 < 25; j0 += 4) {
      if (j0 + q < 25) { s[i] = fmaf(tv, W2s[k * 25 + j0 + q], s[i]); ++i; }
    }
  }
  float racc = 0.f;
  {
    int i = 0;
    #pragma unroll
    for (int j0 = 0; j0 < 25; j0 += 4) {
      if (j0 + q < 25) { racc = fmaf(frelu(s[i]), W3s[j0 + q], racc); ++i; }
    }
  }
  racc += __shfl_xor(racc, 1, 4);
  racc += __shfl_xor(racc, 2, 4);
  if (q == 0) out[base + el] = racc + b3s[0];
}

extern "C" void kernel_launch(void* const* d_in, const int* in_sizes, int n_in,
                              void* d_out, int out_size, void* d_ws, size_t ws_size,
                              hipStream_t stream) {
  (void)in_sizes; (void)n_in; (void)out_size; (void)ws_size;
  const float* x       = (const float*)d_in[0];
  const int*   eidx    = (const int*)  d_in[1];
  const float* eattr   = (const float*)d_in[2];
  const float* node_w  = (const float*)d_in[3];
  const float* node_b  = (const float*)d_in[4];
  const float* edge_w  = (const float*)d_in[5];
  const float* edge_b  = (const float*)d_in[6];
  const float* conv_w1 = (const float*)d_in[7];
  const float* conv_b1 = (const float*)d_in[8];
  const float* conv_w2 = (const float*)d_in[9];
  const float* conv_b2 = (const float*)d_in[10];
  const float* bn_g    = (const float*)d_in[11];
  const float* bn_b    = (const float*)d_in[12];
  const float* em_w1   = (const float*)d_in[13];
  const float* em_b1   = (const float*)d_in[14];
  const float* em_w2   = (const float*)d_in[15];
  const float* em_b2   = (const float*)d_in[16];
  const float* mlp_w1  = (const float*)d_in[17];
  const float* mlp_b1  = (const float*)d_in[18];
  const float* mlp_w2  = (const float*)d_in[19];
  const float* mlp_b2  = (const float*)d_in[20];
  const float* mlp_w3  = (const float*)d_in[21];
  const float* mlp_b3  = (const float*)d_in[22];

  const int* src = eidx;
  const int* dst = eidx + NE;

  // ws budget: exactly 200,000,000 B (round-2-proven). Packed weights alias
  // the agg region (dead between k_node_update and the next layer's memset).
  char* ws = (char*)d_ws;
  float* h   = (float*)(ws);                      // 20,000,000 B
  float* agg = (float*)(ws + 20000000);           // 20,000,000 B
  float* e   = (float*)(ws + 40000000);           // 160,000,000 B
  unsigned short* w1p  = (unsigned short*)(ws + 20000000);            // 71,680 B
  unsigned short* w2p  = (unsigned short*)(ws + 20000000 + 71680);    // 28,672 B
  unsigned short* wf1p = (unsigned short*)(ws + 20000000 + 100352);   // 40,960 B

  k_node_embed<<<(NN * HD + 255) / 256, 256, 0, stream>>>(x, node_w, node_b, h);
  k_edge_embed<<<(NE * HD + 255) / 256, 256, 0, stream>>>(eattr, edge_w, edge_b, e);

  for (int i = 0; i < 2; ++i) {
    hipMemsetAsync(agg, 0, (size_t)NN * HD * sizeof(float), stream);
    long long sth = (long long)NE * 25;
    k_scatter<<<(unsigned)((sth + 255) / 256), 256, 0, stream>>>(h, e, src, dst, agg);
    k_node_update<<<(NN + 63) / 64, 256, 0, stream>>>(
        h, agg, conv_w1 + i * HD * HD, conv_b1 + i * HD,
        conv_w2 + i * HD * HD, conv_b2 + i * HD, bn_g + i * HD, bn_b + i * HD);
    // agg now dead for this layer: pack this layer's edge-MLP weights into it
    k_pack<<<(10 * 7 * 64 + 255) / 256, 256, 0, stream>>>(em_w1 + i * 30000, w1p, 300, 100, 10, 7);
    k_pack<<<(4 * 7 * 64 + 255) / 256, 256, 0, stream>>>(em_w2 + i * 10000,  w2p, 100, 100, 4, 7);
    k_edge_mfma<<<NE / 64, 256, 0, stream>>>(
        h, e, src, dst, w1p, em_b1 + i * HD, w2p, em_b2 + i * HD);
  }

  k_pack<<<(10 * 4 * 64 + 255) / 256, 256, 0, stream>>>(mlp_w1, wf1p, 300, 50, 10, 4);
  k_final_mfma<<<NE / 64, 256, 0, stream>>>(
      h, e, src, dst, wf1p, mlp_b1, mlp_w2, mlp_b2, mlp_w3, mlp_b3, (float*)d_out);
}

// Round 5
// 1440.291 us; speedup vs baseline: 4.7976x; 1.6251x over previous
//
#include <hip/hip_runtime.h>

#define HD 100
#define NF 16
#define EF 8
#define NN 50000
#define NE 400000

typedef __attribute__((ext_vector_type(8))) short bf16x8;
typedef __attribute__((ext_vector_type(4))) float f32x4;

__device__ __forceinline__ float frelu(float v) { return v > 0.f ? v : 0.f; }
__device__ __forceinline__ unsigned short f2bf(float f) {
  unsigned int u = __float_as_uint(f);
  unsigned int r = (u + 0x7FFF + ((u >> 16) & 1)) >> 16;   // RNE
  return (unsigned short)r;
}
// XOR-swizzle: spread bank-aligned rows across 16B slots (G4 / T2)
__device__ __forceinline__ int SWZ(int row, int byte) { return byte ^ ((row & 7) << 4); }

// ---------------- weight pre-pack: W[K][N] fp32 -> frag-linear bf16 ----------------
__global__ __launch_bounds__(256) void k_pack(const float* __restrict__ W,
    unsigned short* __restrict__ out, int K, int N, int KS, int NT) {
  int t = blockIdx.x * 256 + threadIdx.x;
  if (t >= KS * NT * 64) return;
  int lane = t & 63, nt = (t >> 6) % NT, ks = (t >> 6) / NT;
  int kb = ks * 32 + (lane >> 4) * 8, n = nt * 16 + (lane & 15);
  unsigned short v[8];
  #pragma unroll
  for (int j = 0; j < 8; ++j) {
    int k = kb + j;
    float f = (k < K && n < N) ? W[(size_t)k * N + n] : 0.f;
    v[j] = f2bf(f);
  }
  uint4 o4;
  o4.x = (unsigned)v[0] | ((unsigned)v[1] << 16);
  o4.y = (unsigned)v[2] | ((unsigned)v[3] << 16);
  o4.z = (unsigned)v[4] | ((unsigned)v[5] << 16);
  o4.w = (unsigned)v[6] | ((unsigned)v[7] << 16);
  *(uint4*)&out[(size_t)t * 8] = o4;
}

__global__ __launch_bounds__(256) void k_node_embed(const float* __restrict__ x,
    const float* __restrict__ w, const float* __restrict__ b, float* __restrict__ h) {
  int t = blockIdx.x * 256 + threadIdx.x;
  int n = t / HD, o = t % HD;
  if (n >= NN) return;
  float acc = b[o];
  #pragma unroll
  for (int k = 0; k < NF; ++k) acc = fmaf(x[n * NF + k], w[k * HD + o], acc);
  h[(size_t)n * HD + o] = acc;
}

__global__ __launch_bounds__(256) void k_edge_embed(const float* __restrict__ ea,
    const float* __restrict__ w, const float* __restrict__ b, float* __restrict__ e) {
  int t = blockIdx.x * 256 + threadIdx.x;
  int n = t / HD, o = t % HD;
  if (n >= NE) return;
  float acc = b[o];
  #pragma unroll
  for (int k = 0; k < EF; ++k) acc = fmaf(ea[n * EF + k], w[k * HD + o], acc);
  e[(size_t)n * HD + o] = acc;
}

// ---------------- CSR build (edge_index is constant; built once per launch) ----------
__global__ __launch_bounds__(256) void k_hist(const int* __restrict__ dst, int* __restrict__ deg) {
  int eid = blockIdx.x * 256 + threadIdx.x;
  if (eid < NE) atomicAdd(&deg[dst[eid]], 1);
}
__global__ __launch_bounds__(256) void k_scan_part(const int* __restrict__ deg, int* __restrict__ part) {
  __shared__ int sm[256];
  int i = blockIdx.x * 256 + threadIdx.x;
  sm[threadIdx.x] = (i < NN) ? deg[i] : 0;
  __syncthreads();
  for (int s = 128; s > 0; s >>= 1) {
    if (threadIdx.x < s) sm[threadIdx.x] += sm[threadIdx.x + s];
    __syncthreads();
  }
  if (threadIdx.x == 0) part[blockIdx.x] = sm[0];
}
__global__ __launch_bounds__(256) void k_scan_top(int* __restrict__ part, int nb) {
  __shared__ int sm[256];
  int v = (threadIdx.x < nb) ? part[threadIdx.x] : 0;
  sm[threadIdx.x] = v;
  __syncthreads();
  for (int off = 1; off < 256; off <<= 1) {
    int t = (threadIdx.x >= (unsigned)off) ? sm[threadIdx.x - off] : 0;
    __syncthreads();
    sm[threadIdx.x] += t;
    __syncthreads();
  }
  if (threadIdx.x < nb) part[threadIdx.x] = sm[threadIdx.x] - v;  // exclusive
}
__global__ __launch_bounds__(256) void k_scan_fill(const int* __restrict__ deg,
    const int* __restrict__ part, int* __restrict__ rowptr) {
  __shared__ int sm[256];
  int i = blockIdx.x * 256 + threadIdx.x;
  int v = (i < NN) ? deg[i] : 0;
  sm[threadIdx.x] = v;
  __syncthreads();
  for (int off = 1; off < 256; off <<= 1) {
    int t = (threadIdx.x >= (unsigned)off) ? sm[threadIdx.x - off] : 0;
    __syncthreads();
    sm[threadIdx.x] += t;
    __syncthreads();
  }
  if (i <= NN) rowptr[i] = part[blockIdx.x] + sm[threadIdx.x] - v;  // exclusive prefix
}
__global__ __launch_bounds__(256) void k_copy(const int* __restrict__ a, int* __restrict__ b) {
  int i = blockIdx.x * 256 + threadIdx.x;
  if (i < NN) b[i] = a[i];
}
__global__ __launch_bounds__(256) void k_fill(const int* __restrict__ dst,
    int* __restrict__ cursor, int* __restrict__ eids) {
  int eid = blockIdx.x * 256 + threadIdx.x;
  if (eid >= NE) return;
  int pos = atomicAdd(&cursor[dst[eid]], 1);
  eids[pos] = eid;
}

// ---------------- gather-sum agg (no atomics, no memset) ----------------
// 4 threads per node; each owns float4 chunks c = sub, sub+4, ..., of the 25.
__global__ __launch_bounds__(256) void k_gather(const float* __restrict__ h,
    const float* __restrict__ e, const int* __restrict__ rowptr,
    const int* __restrict__ eids, const int* __restrict__ src, float* __restrict__ agg) {
  int slot = threadIdx.x >> 2, sub = threadIdx.x & 3;
  int n = blockIdx.x * 64 + slot;
  if (n >= NN) return;
  int r0 = rowptr[n], r1 = rowptr[n + 1];
  float4 acc[7];
  #pragma unroll
  for (int i = 0; i < 7; ++i) { acc[i].x = 0.f; acc[i].y = 0.f; acc[i].z = 0.f; acc[i].w = 0.f; }
  for (int p = r0; p < r1; ++p) {
    int eid = eids[p];
    int s = src[eid];
    const float4* hp = (const float4*)&h[(size_t)s * HD];
    const float4* ep = (const float4*)&e[(size_t)eid * HD];
    #pragma unroll
    for (int i = 0; i < 7; ++i) {
      int c = sub + i * 4;
      if (c < 25) {
        float4 hv = hp[c], ev = ep[c];
        acc[i].x += frelu(hv.x + ev.x);
        acc[i].y += frelu(hv.y + ev.y);
        acc[i].z += frelu(hv.z + ev.z);
        acc[i].w += frelu(hv.w + ev.w);
      }
    }
  }
  float4* ap = (float4*)&agg[(size_t)n * HD];
  #pragma unroll
  for (int i = 0; i < 7; ++i) {
    int c = sub + i * 4;
    if (c < 25) ap[c] = acc[i];
  }
}

// ---------------- fallback path (small ws): atomic scatter ----------------
__global__ __launch_bounds__(256) void k_scatter(const float* __restrict__ h,
    const float* __restrict__ e, const int* __restrict__ src, const int* __restrict__ dst,
    float* __restrict__ agg) {
  long long t = (long long)blockIdx.x * 256 + threadIdx.x;
  int ei = (int)(t / 25), q = (int)(t % 25) * 4;
  if (ei >= NE) return;
  int s = src[ei], d = dst[ei];
  float4 hv = *(const float4*)&h[(size_t)s * HD + q];
  float4 ev = *(const float4*)&e[(size_t)ei * HD + q];
  float v0 = hv.x + ev.x, v1 = hv.y + ev.y, v2 = hv.z + ev.z, v3 = hv.w + ev.w;
  float* ap = &agg[(size_t)d * HD + q];
  if (v0 > 0.f) atomicAdd(ap + 0, v0);
  if (v1 > 0.f) atomicAdd(ap + 1, v1);
  if (v2 > 0.f) atomicAdd(ap + 2, v2);
  if (v3 > 0.f) atomicAdd(ap + 3, v3);
}

// fp32 node update (accuracy-critical path)
__global__ __launch_bounds__(256) void k_node_update(float* __restrict__ h,
    const float* __restrict__ agg,
    const float* __restrict__ w1, const float* __restrict__ b1,
    const float* __restrict__ w2, const float* __restrict__ b2,
    const float* __restrict__ gamma, const float* __restrict__ beta) {
  __shared__ float zs[64 * 101];
  int tid = threadIdx.x;
  int base = blockIdx.x * 64;
  for (int idx = tid; idx < 64 * HD; idx += 256) {
    int n = idx / HD, k = idx % HD;
    int gn = base + n; int cn = gn < NN ? gn : NN - 1;
    zs[n * 101 + k] = h[(size_t)cn * HD + k] + agg[(size_t)cn * HD + k];
  }
  __syncthreads();
  int el = tid & 63;
  int o0 = __builtin_amdgcn_readfirstlane((tid >> 6) * 25);
  float* row = &zs[el * 101];
  float acc[25];
  #pragma unroll
  for (int j = 0; j < 25; ++j) acc[j] = b1[o0 + j];
  for (int k = 0; k < HD; ++k) {
    float a = row[k];
    const float* wr = &w1[k * HD + o0];
    #pragma unroll
    for (int j = 0; j < 25; ++j) acc[j] = fmaf(a, wr[j], acc[j]);
  }
  __syncthreads();
  #pragma unroll
  for (int j = 0; j < 25; ++j) row[o0 + j] = frelu(acc[j]);
  __syncthreads();
  float acc2[25];
  #pragma unroll
  for (int j = 0; j < 25; ++j) acc2[j] = b2[o0 + j];
  for (int k = 0; k < HD; ++k) {
    float a = row[k];
    const float* wr = &w2[k * HD + o0];
    #pragma unroll
    for (int j = 0; j < 25; ++j) acc2[j] = fmaf(a, wr[j], acc2[j]);
  }
  int gn = base + el;
  if (gn < NN) {
    const float bninv = 0.99999500003749973f;  // 1/sqrt(1+1e-5)
    #pragma unroll
    for (int j = 0; j < 25; ++j) {
      int o = o0 + j;
      float bn = acc2[j] * (gamma[o] * bninv) + beta[o];
      h[(size_t)gn * HD + o] = (h[(size_t)gn * HD + o] + frelu(bn)) * 0.5f;
    }
  }
}

// ---------------- MFMA edge update: 64 edges/block, 4 waves ----------------
__global__ __launch_bounds__(256) void k_edge_mfma(
    const float* __restrict__ h, float* __restrict__ e,
    const int* __restrict__ src, const int* __restrict__ dst,
    const unsigned short* __restrict__ w1p, const float* __restrict__ b1,
    const unsigned short* __restrict__ w2p, const float* __restrict__ b2) {
  __shared__ __align__(16) char lds[55296];
  char* A1 = lds;                 // 64 rows x 640B (A2 phase: 64 x 256B)
  char* WBa = lds + 40960;        // 7168B
  char* WBb = lds + 48128;        // 7168B
  int tid = threadIdx.x;
  int base = blockIdx.x * 64;
  for (int idx = tid; idx < 64 * 75; idx += 256) {
    int row = idx / 75, c4 = idx % 75;
    int ge = base + row;
    const float* sp;
    if (c4 < 25)      sp = &h[(size_t)src[ge] * HD + c4 * 4];
    else if (c4 < 50) sp = &h[(size_t)dst[ge] * HD + (c4 - 25) * 4];
    else              sp = &e[(size_t)ge * HD + (c4 - 50) * 4];
    float4 f = *(const float4*)sp;
    uint2 o;
    o.x = (unsigned)f2bf(f.x) | ((unsigned)f2bf(f.y) << 16);
    o.y = (unsigned)f2bf(f.z) | ((unsigned)f2bf(f.w) << 16);
    *(uint2*)(A1 + SWZ(row, row * 640 + c4 * 8)) = o;
  }
  for (int idx = tid; idx < 64 * 5; idx += 256) {
    int row = idx / 5, j = idx % 5;
    uint2 z; z.x = 0u; z.y = 0u;
    *(uint2*)(A1 + SWZ(row, row * 640 + 600 + j * 8)) = z;
  }
  for (int c = tid; c < 448; c += 256)
    *(uint4*)(WBa + c * 16) = ((const uint4*)w1p)[c];
  __syncthreads();

  int lane = tid & 63, w = tid >> 6;
  int l15 = lane & 15, lq = lane >> 4;
  f32x4 zero = {0.f, 0.f, 0.f, 0.f};
  f32x4 acc[7];
  #pragma unroll
  for (int nt = 0; nt < 7; ++nt) acc[nt] = zero;

  for (int ks = 0; ks < 10; ++ks) {
    char* rb = (ks & 1) ? WBb : WBa;
    char* wb = (ks & 1) ? WBa : WBb;
    uint4 st0, st1;
    if (ks < 9) {
      const uint4* wp = (const uint4*)w1p + (size_t)(ks + 1) * 448;
      st0 = wp[tid];
      if (tid < 192) st1 = wp[256 + tid];
    }
    int arow = w * 16 + l15;
    bf16x8 a = *(const bf16x8*)(A1 + SWZ(arow, arow * 640 + (ks * 32 + lq * 8) * 2));
    #pragma unroll
    for (int nt = 0; nt < 7; ++nt) {
      bf16x8 b = *(const bf16x8*)(rb + (nt * 64 + lane) * 16);
      acc[nt] = __builtin_amdgcn_mfma_f32_16x16x32_bf16(a, b, acc[nt], 0, 0, 0);
    }
    if (ks < 9) {
      *(uint4*)(wb + tid * 16) = st0;
      if (tid < 192) *(uint4*)(wb + (256 + tid) * 16) = st1;
    }
    __syncthreads();
  }

  #pragma unroll
  for (int nt = 0; nt < 7; ++nt) {
    int o = nt * 16 + l15;
    float bias = (o < HD) ? b1[o] : 0.f;
    #pragma unroll
    for (int i = 0; i < 4; ++i) {
      int r = w * 16 + lq * 4 + i;
      float v = acc[nt][i] + bias;
      v = (o < HD) ? frelu(v) : 0.f;
      *(unsigned short*)(A1 + SWZ(r, r * 256 + o * 2)) = f2bf(v);
    }
  }
  for (int idx = tid; idx < 64 * 8; idx += 256) {
    int r = idx / 8, c = idx % 8;
    *(unsigned int*)(A1 + SWZ(r, r * 256 + 224 + c * 4)) = 0;
  }
  for (int c = tid; c < 448; c += 256)
    *(uint4*)(WBa + c * 16) = ((const uint4*)w2p)[c];
  __syncthreads();

  f32x4 acc2[7];
  #pragma unroll
  for (int nt = 0; nt < 7; ++nt) acc2[nt] = zero;
  for (int ks = 0; ks < 4; ++ks) {
    char* rb = (ks & 1) ? WBb : WBa;
    char* wb = (ks & 1) ? WBa : WBb;
    uint4 st0, st1;
    if (ks < 3) {
      const uint4* wp = (const uint4*)w2p + (size_t)(ks + 1) * 448;
      st0 = wp[tid];
      if (tid < 192) st1 = wp[256 + tid];
    }
    int arow = w * 16 + l15;
    bf16x8 a = *(const bf16x8*)(A1 + SWZ(arow, arow * 256 + (ks * 32 + lq * 8) * 2));
    #pragma unroll
    for (int nt = 0; nt < 7; ++nt) {
      bf16x8 b = *(const bf16x8*)(rb + (nt * 64 + lane) * 16);
      acc2[nt] = __builtin_amdgcn_mfma_f32_16x16x32_bf16(a, b, acc2[nt], 0, 0, 0);
    }
    if (ks < 3) {
      *(uint4*)(wb + tid * 16) = st0;
      if (tid < 192) *(uint4*)(wb + (256 + tid) * 16) = st1;
    }
    __syncthreads();
  }
  #pragma unroll
  for (int nt = 0; nt < 7; ++nt) {
    int o = nt * 16 + l15;
    if (o < HD) {
      float bias = b2[o];
      #pragma unroll
      for (int i = 0; i < 4; ++i) {
        int r = w * 16 + lq * 4 + i;
        size_t p = (size_t)(base + r) * HD + o;
        e[p] = e[p] + 0.5f * (acc2[nt][i] + bias);
      }
    }
  }
}

// ---------------- MFMA final MLP: 64 edges/block ----------------
__global__ __launch_bounds__(256) void k_final_mfma(
    const float* __restrict__ h, const float* __restrict__ e,
    const int* __restrict__ src, const int* __restrict__ dst,
    const unsigned short* __restrict__ wf1p, const float* __restrict__ b1,
    const float* __restrict__ w2, const float* __restrict__ b2,
    const float* __restrict__ w3, const float* __restrict__ b3,
    float* __restrict__ out) {
  __shared__ __align__(16) char lds[55296];
  char* A1 = lds;                 // 64 x 640B ; phase2: t fp32 64 x 208B
  char* WBa = lds + 40960;        // 4096B
  char* WBb = lds + 45056;        // 4096B
  float* W2s = (float*)(lds + 49152);   // 1250 floats
  float* b2s = (float*)(lds + 54152);   // 25
  float* W3s = (float*)(lds + 54252);   // 25
  float* b3s = (float*)(lds + 54352);   // 1
  int tid = threadIdx.x;
  int base = blockIdx.x * 64;
  for (int idx = tid; idx < 64 * 75; idx += 256) {
    int row = idx / 75, c4 = idx % 75;
    int ge = base + row;
    const float* sp;
    if (c4 < 25)      sp = &h[(size_t)src[ge] * HD + c4 * 4];
    else if (c4 < 50) sp = &h[(size_t)dst[ge] * HD + (c4 - 25) * 4];
    else              sp = &e[(size_t)ge * HD + (c4 - 50) * 4];
    float4 f = *(const float4*)sp;
    uint2 o;
    o.x = (unsigned)f2bf(f.x) | ((unsigned)f2bf(f.y) << 16);
    o.y = (unsigned)f2bf(f.z) | ((unsigned)f2bf(f.w) << 16);
    *(uint2*)(A1 + SWZ(row, row * 640 + c4 * 8)) = o;
  }
  for (int idx = tid; idx < 64 * 5; idx += 256) {
    int row = idx / 5, j = idx % 5;
    uint2 z; z.x = 0u; z.y = 0u;
    *(uint2*)(A1 + SWZ(row, row * 640 + 600 + j * 8)) = z;
  }
  for (int c = tid; c < 256; c += 256) *(uint4*)(WBa + c * 16) = ((const uint4*)wf1p)[c];
  for (int c = tid; c < 1250; c += 256) W2s[c] = w2[c];
  if (tid < 25) { b2s[tid] = b2[tid]; W3s[tid] = w3[tid]; }
  if (tid == 0) b3s[0] = b3[0];
  __syncthreads();

  int lane = tid & 63, w = tid >> 6;
  int l15 = lane & 15, lq = lane >> 4;
  f32x4 zero = {0.f, 0.f, 0.f, 0.f};
  f32x4 acc[4];
  #pragma unroll
  for (int nt = 0; nt < 4; ++nt) acc[nt] = zero;
  for (int ks = 0; ks < 10; ++ks) {
    char* rb = (ks & 1) ? WBb : WBa;
    char* wb = (ks & 1) ? WBa : WBb;
    uint4 st0;
    if (ks < 9) st0 = ((const uint4*)wf1p)[(size_t)(ks + 1) * 256 + tid];
    int arow = w * 16 + l15;
    bf16x8 a = *(const bf16x8*)(A1 + SWZ(arow, arow * 640 + (ks * 32 + lq * 8) * 2));
    #pragma unroll
    for (int nt = 0; nt < 4; ++nt) {
      bf16x8 b = *(const bf16x8*)(rb + (nt * 64 + lane) * 16);
      acc[nt] = __builtin_amdgcn_mfma_f32_16x16x32_bf16(a, b, acc[nt], 0, 0, 0);
    }
    if (ks < 9) *(uint4*)(wb + tid * 16) = st0;
    __syncthreads();
  }
  #pragma unroll
  for (int nt = 0; nt < 4; ++nt) {
    int o = nt * 16 + l15;
    if (o < 50) {
      float bias = b1[o];
      #pragma unroll
      for (int i = 0; i < 4; ++i) {
        int r = w * 16 + lq * 4 + i;
        *(float*)(A1 + r * 208 + o * 4) = frelu(acc[nt][i] + bias);
      }
    }
  }
  __syncthreads();
  int el = tid >> 2, q = tid & 3;
  const float* trow = (const float*)(A1 + el * 208);
  float s[7];
  {
    int i = 0;
    #pragma unroll
    for (int j0 = 0; j0 < 25; j0 += 4) { if (j0 + q < 25) s[i++] = b2s[j0 + q]; }
  }
  for (int k = 0; k < 50; ++k) {
    float tv = trow[k];
    int i = 0;
    #pragma unroll
    for (int j0 = 0; j0 < 25; j0 += 4) {
      if (j0 + q < 25) { s[i] = fmaf(tv, W2s[k * 25 + j0 + q], s[i]); ++i; }
    }
  }
  float racc = 0.f;
  {
    int i = 0;
    #pragma unroll
    for (int j0 = 0; j0 < 25; j0 += 4) {
      if (j0 + q < 25) { racc = fmaf(frelu(s[i]), W3s[j0 + q], racc); ++i; }
    }
  }
  racc += __shfl_xor(racc, 1, 4);
  racc += __shfl_xor(racc, 2, 4);
  if (q == 0) out[base + el] = racc + b3s[0];
}

extern "C" void kernel_launch(void* const* d_in, const int* in_sizes, int n_in,
                              void* d_out, int out_size, void* d_ws, size_t ws_size,
                              hipStream_t stream) {
  (void)in_sizes; (void)n_in; (void)out_size;
  const float* x       = (const float*)d_in[0];
  const int*   eidx    = (const int*)  d_in[1];
  const float* eattr   = (const float*)d_in[2];
  const float* node_w  = (const float*)d_in[3];
  const float* node_b  = (const float*)d_in[4];
  const float* edge_w  = (const float*)d_in[5];
  const float* edge_b  = (const float*)d_in[6];
  const float* conv_w1 = (const float*)d_in[7];
  const float* conv_b1 = (const float*)d_in[8];
  const float* conv_w2 = (const float*)d_in[9];
  const float* conv_b2 = (const float*)d_in[10];
  const float* bn_g    = (const float*)d_in[11];
  const float* bn_b    = (const float*)d_in[12];
  const float* em_w1   = (const float*)d_in[13];
  const float* em_b1   = (const float*)d_in[14];
  const float* em_w2   = (const float*)d_in[15];
  const float* em_b2   = (const float*)d_in[16];
  const float* mlp_w1  = (const float*)d_in[17];
  const float* mlp_b1  = (const float*)d_in[18];
  const float* mlp_w2  = (const float*)d_in[19];
  const float* mlp_b2  = (const float*)d_in[20];
  const float* mlp_w3  = (const float*)d_in[21];
  const float* mlp_b3  = (const float*)d_in[22];

  const int* src = eidx;
  const int* dst = eidx + NE;

  char* ws = (char*)d_ws;
  float* h   = (float*)(ws);                      // 20,000,000 B
  float* agg = (float*)(ws + 20000000);           // 20,000,000 B
  float* e   = (float*)(ws + 40000000);           // 160,000,000 B

  // Path A (ws >= 203 MB): CSR + extras above 200 MB. Path B: round-4 layout.
  bool big = ws_size >= 203000000ULL;
  size_t wbase = big ? 200000000ULL : 20000000ULL;  // small-ws: alias agg (dead there)
  unsigned short* w1p  = (unsigned short*)(ws + wbase);
  unsigned short* w2p  = (unsigned short*)(ws + wbase + 71680);
  unsigned short* wf1p = (unsigned short*)(ws + wbase + 100352);
  int* rowptr = (int*)(ws + 200141312);   // 50,001 (+pad) ints
  int* cursor = (int*)(ws + 200342020);   // 50,000 ints (deg, then fill cursor)
  int* eids   = (int*)(ws + 200542020);   // 400,000 ints
  int* part   = (int*)(ws + 202142020);   // 256 ints

  k_node_embed<<<(NN * HD + 255) / 256, 256, 0, stream>>>(x, node_w, node_b, h);
  k_edge_embed<<<(NE * HD + 255) / 256, 256, 0, stream>>>(eattr, edge_w, edge_b, e);

  const int SCAN_NB = (NN + 256) / 256;  // 196 blocks covers i <= NN
  if (big) {
    hipMemsetAsync(cursor, 0, (size_t)NN * 4, stream);
    k_hist<<<(NE + 255) / 256, 256, 0, stream>>>(dst, cursor);
    k_scan_part<<<SCAN_NB, 256, 0, stream>>>(cursor, part);
    k_scan_top<<<1, 256, 0, stream>>>(part, SCAN_NB);
    k_scan_fill<<<SCAN_NB, 256, 0, stream>>>(cursor, part, rowptr);
    k_copy<<<SCAN_NB, 256, 0, stream>>>(rowptr, cursor);
    k_fill<<<(NE + 255) / 256, 256, 0, stream>>>(dst, cursor, eids);
  }

  for (int i = 0; i < 2; ++i) {
    if (big) {
      k_gather<<<(NN + 63) / 64, 256, 0, stream>>>(h, e, rowptr, eids, src, agg);
    } else {
      hipMemsetAsync(agg, 0, (size_t)NN * HD * sizeof(float), stream);
      long long sth = (long long)NE * 25;
      k_scatter<<<(unsigned)((sth + 255) / 256), 256, 0, stream>>>(h, e, src, dst, agg);
    }
    k_node_update<<<(NN + 63) / 64, 256, 0, stream>>>(
        h, agg, conv_w1 + i * HD * HD, conv_b1 + i * HD,
        conv_w2 + i * HD * HD, conv_b2 + i * HD, bn_g + i * HD, bn_b + i * HD);
    k_pack<<<(10 * 7 * 64 + 255) / 256, 256, 0, stream>>>(em_w1 + i * 30000, w1p, 300, 100, 10, 7);
    k_pack<<<(4 * 7 * 64 + 255) / 256, 256, 0, stream>>>(em_w2 + i * 10000,  w2p, 100, 100, 4, 7);
    k_edge_mfma<<<NE / 64, 256, 0, stream>>>(
        h, e, src, dst, w1p, em_b1 + i * HD, w2p, em_b2 + i * HD);
  }

  k_pack<<<(10 * 4 * 64 + 255) / 256, 256, 0, stream>>>(mlp_w1, wf1p, 300, 50, 10, 4);
  k_final_mfma<<<NE / 64, 256, 0, stream>>>(
      h, e, src, dst, wf1p, mlp_b1, mlp_w2, mlp_b2, mlp_w3, mlp_b3, (float*)d_out);
}

// Round 6
// 1029.425 us; speedup vs baseline: 6.7124x; 1.3991x over previous
//
#include <hip/hip_runtime.h>

#define HD 100
#define NF 16
#define EF 8
#define NN 50000
#define NE 400000

typedef __attribute__((ext_vector_type(8))) short bf16x8;
typedef __attribute__((ext_vector_type(4))) float f32x4;

__device__ __forceinline__ float frelu(float v) { return v > 0.f ? v : 0.f; }
__device__ __forceinline__ unsigned short f2bf(float f) {
  unsigned int u = __float_as_uint(f);
  unsigned int r = (u + 0x7FFF + ((u >> 16) & 1)) >> 16;   // RNE
  return (unsigned short)r;
}
// XOR-swizzle: spread bank-aligned rows across 16B slots (G4 / T2)
__device__ __forceinline__ int SWZ(int row, int byte) { return byte ^ ((row & 7) << 4); }

// ---------------- weight pre-pack: W[K][N] fp32 -> frag-linear bf16 ----------------
__global__ __launch_bounds__(256) void k_pack(const float* __restrict__ W,
    unsigned short* __restrict__ out, int K, int N, int KS, int NT) {
  int t = blockIdx.x * 256 + threadIdx.x;
  if (t >= KS * NT * 64) return;
  int lane = t & 63, nt = (t >> 6) % NT, ks = (t >> 6) / NT;
  int kb = ks * 32 + (lane >> 4) * 8, n = nt * 16 + (lane & 15);
  unsigned short v[8];
  #pragma unroll
  for (int j = 0; j < 8; ++j) {
    int k = kb + j;
    float f = (k < K && n < N) ? W[(size_t)k * N + n] : 0.f;
    v[j] = f2bf(f);
  }
  uint4 o4;
  o4.x = (unsigned)v[0] | ((unsigned)v[1] << 16);
  o4.y = (unsigned)v[2] | ((unsigned)v[3] << 16);
  o4.z = (unsigned)v[4] | ((unsigned)v[5] << 16);
  o4.w = (unsigned)v[6] | ((unsigned)v[7] << 16);
  *(uint4*)&out[(size_t)t * 8] = o4;
}

__global__ __launch_bounds__(256) void k_node_embed(const float* __restrict__ x,
    const float* __restrict__ w, const float* __restrict__ b, float* __restrict__ h) {
  int t = blockIdx.x * 256 + threadIdx.x;
  int n = t / HD, o = t % HD;
  if (n >= NN) return;
  float acc = b[o];
  #pragma unroll
  for (int k = 0; k < NF; ++k) acc = fmaf(x[n * NF + k], w[k * HD + o], acc);
  h[(size_t)n * HD + o] = acc;
}

// e stored in PERMUTED (dst-sorted) layout: row p corresponds to edge eids[p]
__global__ __launch_bounds__(256) void k_edge_embed_perm(const float* __restrict__ ea,
    const int* __restrict__ eids, const float* __restrict__ w, const float* __restrict__ b,
    float* __restrict__ e) {
  int t = blockIdx.x * 256 + threadIdx.x;
  int p = t / HD, o = t % HD;
  if (p >= NE) return;
  int eid = eids[p];
  float acc = b[o];
  #pragma unroll
  for (int k = 0; k < EF; ++k) acc = fmaf(ea[(size_t)eid * EF + k], w[k * HD + o], acc);
  e[(size_t)p * HD + o] = acc;
}

// ---------------- CSR build (edge_index constant; rebuilt every launch) ----------
__global__ __launch_bounds__(256) void k_hist(const int* __restrict__ dst, int* __restrict__ deg) {
  int eid = blockIdx.x * 256 + threadIdx.x;
  if (eid < NE) atomicAdd(&deg[dst[eid]], 1);
}
__global__ __launch_bounds__(256) void k_scan_part(const int* __restrict__ deg, int* __restrict__ part) {
  __shared__ int sm[256];
  int i = blockIdx.x * 256 + threadIdx.x;
  sm[threadIdx.x] = (i < NN) ? deg[i] : 0;
  __syncthreads();
  for (int s = 128; s > 0; s >>= 1) {
    if (threadIdx.x < s) sm[threadIdx.x] += sm[threadIdx.x + s];
    __syncthreads();
  }
  if (threadIdx.x == 0) part[blockIdx.x] = sm[0];
}
__global__ __launch_bounds__(256) void k_scan_top(int* __restrict__ part, int nb) {
  __shared__ int sm[256];
  int v = (threadIdx.x < nb) ? part[threadIdx.x] : 0;
  sm[threadIdx.x] = v;
  __syncthreads();
  for (int off = 1; off < 256; off <<= 1) {
    int t = (threadIdx.x >= (unsigned)off) ? sm[threadIdx.x - off] : 0;
    __syncthreads();
    sm[threadIdx.x] += t;
    __syncthreads();
  }
  if (threadIdx.x < nb) part[threadIdx.x] = sm[threadIdx.x] - v;  // exclusive
}
__global__ __launch_bounds__(256) void k_scan_fill(const int* __restrict__ deg,
    const int* __restrict__ part, int* __restrict__ rowptr) {
  __shared__ int sm[256];
  int i = blockIdx.x * 256 + threadIdx.x;
  int v = (i < NN) ? deg[i] : 0;
  sm[threadIdx.x] = v;
  __syncthreads();
  for (int off = 1; off < 256; off <<= 1) {
    int t = (threadIdx.x >= (unsigned)off) ? sm[threadIdx.x - off] : 0;
    __syncthreads();
    sm[threadIdx.x] += t;
    __syncthreads();
  }
  if (i <= NN) rowptr[i] = part[blockIdx.x] + sm[threadIdx.x] - v;  // exclusive prefix
}
__global__ __launch_bounds__(256) void k_copy(const int* __restrict__ a, int* __restrict__ b) {
  int i = blockIdx.x * 256 + threadIdx.x;
  if (i < NN) b[i] = a[i];
}
__global__ __launch_bounds__(256) void k_fill(const int* __restrict__ dst,
    int* __restrict__ cursor, int* __restrict__ eids) {
  int eid = blockIdx.x * 256 + threadIdx.x;
  if (eid >= NE) return;
  int pos = atomicAdd(&cursor[dst[eid]], 1);
  eids[pos] = eid;
}

// ---------------- gather-sum agg (sequential e, no atomics, no memset) --------------
// 4 threads per node; each owns float4 chunks c = sub, sub+4, ... of the 25.
__global__ __launch_bounds__(256) void k_gather(const float* __restrict__ h,
    const float* __restrict__ e, const int* __restrict__ rowptr,
    const int* __restrict__ eids, const int* __restrict__ src, float* __restrict__ agg) {
  int slot = threadIdx.x >> 2, sub = threadIdx.x & 3;
  int n = blockIdx.x * 64 + slot;
  if (n >= NN) return;
  int r0 = rowptr[n], r1 = rowptr[n + 1];
  float4 acc[7];
  #pragma unroll
  for (int i = 0; i < 7; ++i) { acc[i].x = 0.f; acc[i].y = 0.f; acc[i].z = 0.f; acc[i].w = 0.f; }
  for (int p = r0; p < r1; ++p) {
    int s = src[eids[p]];
    const float4* hp = (const float4*)&h[(size_t)s * HD];
    const float4* ep = (const float4*)&e[(size_t)p * HD];   // sequential rows
    #pragma unroll
    for (int i = 0; i < 7; ++i) {
      int c = sub + i * 4;
      if (c < 25) {
        float4 hv = hp[c], ev = ep[c];
        acc[i].x += frelu(hv.x + ev.x);
        acc[i].y += frelu(hv.y + ev.y);
        acc[i].z += frelu(hv.z + ev.z);
        acc[i].w += frelu(hv.w + ev.w);
      }
    }
  }
  float4* ap = (float4*)&agg[(size_t)n * HD];
  #pragma unroll
  for (int i = 0; i < 7; ++i) {
    int c = sub + i * 4;
    if (c < 25) ap[c] = acc[i];
  }
}

// fp32 node update (accuracy-critical path)
__global__ __launch_bounds__(256) void k_node_update(float* __restrict__ h,
    const float* __restrict__ agg,
    const float* __restrict__ w1, const float* __restrict__ b1,
    const float* __restrict__ w2, const float* __restrict__ b2,
    const float* __restrict__ gamma, const float* __restrict__ beta) {
  __shared__ float zs[64 * 101];
  int tid = threadIdx.x;
  int base = blockIdx.x * 64;
  for (int idx = tid; idx < 64 * HD; idx += 256) {
    int n = idx / HD, k = idx % HD;
    int gn = base + n; int cn = gn < NN ? gn : NN - 1;
    zs[n * 101 + k] = h[(size_t)cn * HD + k] + agg[(size_t)cn * HD + k];
  }
  __syncthreads();
  int el = tid & 63;
  int o0 = __builtin_amdgcn_readfirstlane((tid >> 6) * 25);
  float* row = &zs[el * 101];
  float acc[25];
  #pragma unroll
  for (int j = 0; j < 25; ++j) acc[j] = b1[o0 + j];
  for (int k = 0; k < HD; ++k) {
    float a = row[k];
    const float* wr = &w1[k * HD + o0];
    #pragma unroll
    for (int j = 0; j < 25; ++j) acc[j] = fmaf(a, wr[j], acc[j]);
  }
  __syncthreads();
  #pragma unroll
  for (int j = 0; j < 25; ++j) row[o0 + j] = frelu(acc[j]);
  __syncthreads();
  float acc2[25];
  #pragma unroll
  for (int j = 0; j < 25; ++j) acc2[j] = b2[o0 + j];
  for (int k = 0; k < HD; ++k) {
    float a = row[k];
    const float* wr = &w2[k * HD + o0];
    #pragma unroll
    for (int j = 0; j < 25; ++j) acc2[j] = fmaf(a, wr[j], acc2[j]);
  }
  int gn = base + el;
  if (gn < NN) {
    const float bninv = 0.99999500003749973f;  // 1/sqrt(1+1e-5)
    #pragma unroll
    for (int j = 0; j < 25; ++j) {
      int o = o0 + j;
      float bn = acc2[j] * (gamma[o] * bninv) + beta[o];
      h[(size_t)gn * HD + o] = (h[(size_t)gn * HD + o] + frelu(bn)) * 0.5f;
    }
  }
}

// ---------------- layer-1 MFMA edge update (writes e, permuted rows) ----------------
__global__ __launch_bounds__(256) void k_edge_mfma(
    const float* __restrict__ h, float* __restrict__ e,
    const int* __restrict__ eids, const int* __restrict__ src, const int* __restrict__ dst,
    const unsigned short* __restrict__ w1p, const float* __restrict__ b1,
    const unsigned short* __restrict__ w2p, const float* __restrict__ b2) {
  __shared__ __align__(16) char lds[55808];
  char* A1 = lds;                  // 64 x 640B bf16 A-tile; later C2 fp32 [64][104] stride 416
  char* WBa = lds + 40960;         // 7168
  char* WBb = lds + 48128;         // 7168
  int* ss = (int*)(lds + 55296);   // 64 src
  int* ds_ = ss + 64;              // 64 dst
  int tid = threadIdx.x;
  int base = blockIdx.x * 64;
  if (tid < 64) { int eid = eids[base + tid]; ss[tid] = src[eid]; ds_[tid] = dst[eid]; }
  __syncthreads();
  // stage A1: e (sequential), h_src, h_dst — divergence-free split loops
  for (int idx = tid; idx < 64 * 25; idx += 256) {
    int row = idx / 25, c4 = idx % 25;
    float4 f = ((const float4*)e)[(size_t)(base + row) * 25 + c4];
    uint2 o; o.x = (unsigned)f2bf(f.x) | ((unsigned)f2bf(f.y) << 16);
    o.y = (unsigned)f2bf(f.z) | ((unsigned)f2bf(f.w) << 16);
    *(uint2*)(A1 + SWZ(row, row * 640 + 400 + c4 * 8)) = o;
  }
  for (int idx = tid; idx < 64 * 25; idx += 256) {
    int row = idx / 25, c4 = idx % 25;
    float4 f = ((const float4*)h)[(size_t)ss[row] * 25 + c4];
    uint2 o; o.x = (unsigned)f2bf(f.x) | ((unsigned)f2bf(f.y) << 16);
    o.y = (unsigned)f2bf(f.z) | ((unsigned)f2bf(f.w) << 16);
    *(uint2*)(A1 + SWZ(row, row * 640 + c4 * 8)) = o;
  }
  for (int idx = tid; idx < 64 * 25; idx += 256) {
    int row = idx / 25, c4 = idx % 25;
    float4 f = ((const float4*)h)[(size_t)ds_[row] * 25 + c4];
    uint2 o; o.x = (unsigned)f2bf(f.x) | ((unsigned)f2bf(f.y) << 16);
    o.y = (unsigned)f2bf(f.z) | ((unsigned)f2bf(f.w) << 16);
    *(uint2*)(A1 + SWZ(row, row * 640 + 200 + c4 * 8)) = o;
  }
  for (int idx = tid; idx < 64 * 5; idx += 256) {
    int row = idx / 5, j = idx % 5;
    uint2 z; z.x = 0u; z.y = 0u;
    *(uint2*)(A1 + SWZ(row, row * 640 + 600 + j * 8)) = z;
  }
  for (int c = tid; c < 448; c += 256)
    *(uint4*)(WBa + c * 16) = ((const uint4*)w1p)[c];
  __syncthreads();

  int lane = tid & 63, w = tid >> 6;
  int l15 = lane & 15, lq = lane >> 4;
  f32x4 zero = {0.f, 0.f, 0.f, 0.f};
  f32x4 acc[7];
  #pragma unroll
  for (int nt = 0; nt < 7; ++nt) acc[nt] = zero;
  for (int ks = 0; ks < 10; ++ks) {
    char* rb = (ks & 1) ? WBb : WBa;
    char* wb = (ks & 1) ? WBa : WBb;
    uint4 st0, st1;
    if (ks < 9) {
      const uint4* wp = (const uint4*)w1p + (size_t)(ks + 1) * 448;
      st0 = wp[tid];
      if (tid < 192) st1 = wp[256 + tid];
    }
    int arow = w * 16 + l15;
    bf16x8 a = *(const bf16x8*)(A1 + SWZ(arow, arow * 640 + (ks * 32 + lq * 8) * 2));
    #pragma unroll
    for (int nt = 0; nt < 7; ++nt) {
      bf16x8 b = *(const bf16x8*)(rb + (nt * 64 + lane) * 16);
      acc[nt] = __builtin_amdgcn_mfma_f32_16x16x32_bf16(a, b, acc[nt], 0, 0, 0);
    }
    if (ks < 9) {
      *(uint4*)(wb + tid * 16) = st0;
      if (tid < 192) *(uint4*)(wb + (256 + tid) * 16) = st1;
    }
    __syncthreads();
  }
  // epilogue1: relu(C1+b1) -> bf16 A2 [64][128] stride 256 (overlaps dead A1)
  #pragma unroll
  for (int nt = 0; nt < 7; ++nt) {
    int o = nt * 16 + l15;
    float bias = (o < HD) ? b1[o] : 0.f;
    #pragma unroll
    for (int i = 0; i < 4; ++i) {
      int r = w * 16 + lq * 4 + i;
      float v = acc[nt][i] + bias;
      v = (o < HD) ? frelu(v) : 0.f;
      *(unsigned short*)(A1 + SWZ(r, r * 256 + o * 2)) = f2bf(v);
    }
  }
  for (int idx = tid; idx < 64 * 8; idx += 256) {
    int r = idx / 8, c = idx % 8;
    *(unsigned int*)(A1 + SWZ(r, r * 256 + 224 + c * 4)) = 0;
  }
  for (int c = tid; c < 448; c += 256)
    *(uint4*)(WBa + c * 16) = ((const uint4*)w2p)[c];
  __syncthreads();

  f32x4 acc2[7];
  #pragma unroll
  for (int nt = 0; nt < 7; ++nt) acc2[nt] = zero;
  for (int ks = 0; ks < 4; ++ks) {
    char* rb = (ks & 1) ? WBb : WBa;
    char* wb = (ks & 1) ? WBa : WBb;
    uint4 st0, st1;
    if (ks < 3) {
      const uint4* wp = (const uint4*)w2p + (size_t)(ks + 1) * 448;
      st0 = wp[tid];
      if (tid < 192) st1 = wp[256 + tid];
    }
    int arow = w * 16 + l15;
    bf16x8 a = *(const bf16x8*)(A1 + SWZ(arow, arow * 256 + (ks * 32 + lq * 8) * 2));
    #pragma unroll
    for (int nt = 0; nt < 7; ++nt) {
      bf16x8 b = *(const bf16x8*)(rb + (nt * 64 + lane) * 16);
      acc2[nt] = __builtin_amdgcn_mfma_f32_16x16x32_bf16(a, b, acc2[nt], 0, 0, 0);
    }
    if (ks < 3) {
      *(uint4*)(wb + tid * 16) = st0;
      if (tid < 192) *(uint4*)(wb + (256 + tid) * 16) = st1;
    }
    __syncthreads();
  }
  // epilogue2a: C2+b2 fp32 -> A1 as [64][104] stride 416 (whole A1 dead now)
  #pragma unroll
  for (int nt = 0; nt < 7; ++nt) {
    int o = nt * 16 + l15;
    if (o < HD) {
      float bias = b2[o];
      #pragma unroll
      for (int i = 0; i < 4; ++i) {
        int r = w * 16 + lq * 4 + i;
        *(float*)(A1 + r * 416 + o * 4) = acc2[nt][i] + bias;
      }
    }
  }
  __syncthreads();
  // epilogue2b: coalesced float4 RMW of e
  for (int idx = tid; idx < 64 * 25; idx += 256) {
    int row = idx / 25, c4 = idx % 25;
    float4 c = *(const float4*)(A1 + row * 416 + c4 * 16);
    float4* ep = &((float4*)e)[(size_t)(base + row) * 25 + c4];
    float4 v = *ep;
    v.x += 0.5f * c.x; v.y += 0.5f * c.y; v.z += 0.5f * c.z; v.w += 0.5f * c.w;
    *ep = v;
  }
}

// ------- layer-2 edge update FUSED with final MLP (no e write; out scatter) -------
__global__ __launch_bounds__(256) void k_edge_final_mfma(
    const float* __restrict__ h, const float* __restrict__ e,
    const int* __restrict__ eids, const int* __restrict__ src, const int* __restrict__ dst,
    const unsigned short* __restrict__ w1p, const float* __restrict__ b1,
    const unsigned short* __restrict__ w2p, const float* __restrict__ b2,
    const unsigned short* __restrict__ wf1p, const float* __restrict__ fb1,
    const float* __restrict__ fw2, const float* __restrict__ fb2,
    const float* __restrict__ fw3, const float* __restrict__ fb3,
    float* __restrict__ out) {
  __shared__ __align__(16) char lds[77652];
  char* A1 = lds;                       // 64 x 640B, intact through final GEMM
  char* A2 = lds + 40960;               // 64 x 256B bf16 ; later t fp32 [64][52] stride 208
  char* WBa = lds + 57344;              // 7168
  char* WBb = lds + 64512;              // 7168
  float* W2s = (float*)(lds + 71680);   // 1250
  float* b2s = (float*)(lds + 76680);   // 25
  float* W3s = (float*)(lds + 76780);   // 25
  float* b3s = (float*)(lds + 76880);   // 1
  int* es  = (int*)(lds + 76884);       // 64
  int* ss  = es + 64;
  int* ds_ = ss + 64;
  int tid = threadIdx.x;
  int base = blockIdx.x * 64;
  if (tid < 64) { int eid = eids[base + tid]; es[tid] = eid; ss[tid] = src[eid]; ds_[tid] = dst[eid]; }
  for (int c = tid; c < 1250; c += 256) W2s[c] = fw2[c];
  if (tid < 25) { b2s[tid] = fb2[tid]; W3s[tid] = fw3[tid]; }
  if (tid == 0) b3s[0] = fb3[0];
  __syncthreads();
  for (int idx = tid; idx < 64 * 25; idx += 256) {
    int row = idx / 25, c4 = idx % 25;
    float4 f = ((const float4*)e)[(size_t)(base + row) * 25 + c4];
    uint2 o; o.x = (unsigned)f2bf(f.x) | ((unsigned)f2bf(f.y) << 16);
    o.y = (unsigned)f2bf(f.z) | ((unsigned)f2bf(f.w) << 16);
    *(uint2*)(A1 + SWZ(row, row * 640 + 400 + c4 * 8)) = o;
  }
  for (int idx = tid; idx < 64 * 25; idx += 256) {
    int row = idx / 25, c4 = idx % 25;
    float4 f = ((const float4*)h)[(size_t)ss[row] * 25 + c4];
    uint2 o; o.x = (unsigned)f2bf(f.x) | ((unsigned)f2bf(f.y) << 16);
    o.y = (unsigned)f2bf(f.z) | ((unsigned)f2bf(f.w) << 16);
    *(uint2*)(A1 + SWZ(row, row * 640 + c4 * 8)) = o;
  }
  for (int idx = tid; idx < 64 * 25; idx += 256) {
    int row = idx / 25, c4 = idx % 25;
    float4 f = ((const float4*)h)[(size_t)ds_[row] * 25 + c4];
    uint2 o; o.x = (unsigned)f2bf(f.x) | ((unsigned)f2bf(f.y) << 16);
    o.y = (unsigned)f2bf(f.z) | ((unsigned)f2bf(f.w) << 16);
    *(uint2*)(A1 + SWZ(row, row * 640 + 200 + c4 * 8)) = o;
  }
  for (int idx = tid; idx < 64 * 5; idx += 256) {
    int row = idx / 5, j = idx % 5;
    uint2 z; z.x = 0u; z.y = 0u;
    *(uint2*)(A1 + SWZ(row, row * 640 + 600 + j * 8)) = z;
  }
  for (int c = tid; c < 448; c += 256)
    *(uint4*)(WBa + c * 16) = ((const uint4*)w1p)[c];
  __syncthreads();

  int lane = tid & 63, w = tid >> 6;
  int l15 = lane & 15, lq = lane >> 4;
  f32x4 zero = {0.f, 0.f, 0.f, 0.f};
  // -------- GEMM1: A1[64x320] @ W1[320x112] --------
  f32x4 acc[7];
  #pragma unroll
  for (int nt = 0; nt < 7; ++nt) acc[nt] = zero;
  for (int ks = 0; ks < 10; ++ks) {
    char* rb = (ks & 1) ? WBb : WBa;
    char* wb = (ks & 1) ? WBa : WBb;
    uint4 st0, st1;
    if (ks < 9) {
      const uint4* wp = (const uint4*)w1p + (size_t)(ks + 1) * 448;
      st0 = wp[tid];
      if (tid < 192) st1 = wp[256 + tid];
    }
    int arow = w * 16 + l15;
    bf16x8 a = *(const bf16x8*)(A1 + SWZ(arow, arow * 640 + (ks * 32 + lq * 8) * 2));
    #pragma unroll
    for (int nt = 0; nt < 7; ++nt) {
      bf16x8 b = *(const bf16x8*)(rb + (nt * 64 + lane) * 16);
      acc[nt] = __builtin_amdgcn_mfma_f32_16x16x32_bf16(a, b, acc[nt], 0, 0, 0);
    }
    if (ks < 9) {
      *(uint4*)(wb + tid * 16) = st0;
      if (tid < 192) *(uint4*)(wb + (256 + tid) * 16) = st1;
    }
    __syncthreads();
  }
  // epilogue1: relu(C1+b1) -> bf16 A2 (separate region; A1 stays intact)
  #pragma unroll
  for (int nt = 0; nt < 7; ++nt) {
    int o = nt * 16 + l15;
    float bias = (o < HD) ? b1[o] : 0.f;
    #pragma unroll
    for (int i = 0; i < 4; ++i) {
      int r = w * 16 + lq * 4 + i;
      float v = acc[nt][i] + bias;
      v = (o < HD) ? frelu(v) : 0.f;
      *(unsigned short*)(A2 + SWZ(r, r * 256 + o * 2)) = f2bf(v);
    }
  }
  for (int idx = tid; idx < 64 * 8; idx += 256) {
    int r = idx / 8, c = idx % 8;
    *(unsigned int*)(A2 + SWZ(r, r * 256 + 224 + c * 4)) = 0;
  }
  for (int c = tid; c < 448; c += 256)
    *(uint4*)(WBa + c * 16) = ((const uint4*)w2p)[c];
  __syncthreads();
  // -------- GEMM2: A2[64x128] @ W2[128x112] --------
  f32x4 acc2[7];
  #pragma unroll
  for (int nt = 0; nt < 7; ++nt) acc2[nt] = zero;
  for (int ks = 0; ks < 4; ++ks) {
    char* rb = (ks & 1) ? WBb : WBa;
    char* wb = (ks & 1) ? WBa : WBb;
    uint4 st0, st1;
    if (ks < 3) {
      const uint4* wp = (const uint4*)w2p + (size_t)(ks + 1) * 448;
      st0 = wp[tid];
      if (tid < 192) st1 = wp[256 + tid];
    }
    int arow = w * 16 + l15;
    bf16x8 a = *(const bf16x8*)(A2 + SWZ(arow, arow * 256 + (ks * 32 + lq * 8) * 2));
    #pragma unroll
    for (int nt = 0; nt < 7; ++nt) {
      bf16x8 b = *(const bf16x8*)(rb + (nt * 64 + lane) * 16);
      acc2[nt] = __builtin_amdgcn_mfma_f32_16x16x32_bf16(a, b, acc2[nt], 0, 0, 0);
    }
    if (ks < 3) {
      *(uint4*)(wb + tid * 16) = st0;
      if (tid < 192) *(uint4*)(wb + (256 + tid) * 16) = st1;
    }
    __syncthreads();
  }
  // epilogue2: e_new = e + 0.5*(C2+b2); bf16(e_new) back into A1 cols 200..299 (no e write)
  #pragma unroll
  for (int nt = 0; nt < 7; ++nt) {
    int o = nt * 16 + l15;
    if (o < HD) {
      float bias = b2[o];
      #pragma unroll
      for (int i = 0; i < 4; ++i) {
        int r = w * 16 + lq * 4 + i;
        float ne = e[(size_t)(base + r) * HD + o] + 0.5f * (acc2[nt][i] + bias);
        *(unsigned short*)(A1 + SWZ(r, r * 640 + 400 + o * 2)) = f2bf(ne);
      }
    }
  }
  for (int c = tid; c < 256; c += 256)
    *(uint4*)(WBa + c * 16) = ((const uint4*)wf1p)[c];
  __syncthreads();
  // -------- GEMM3 (final L1): A1[64x320] @ Wf[320x64] --------
  f32x4 acc3[4];
  #pragma unroll
  for (int nt = 0; nt < 4; ++nt) acc3[nt] = zero;
  for (int ks = 0; ks < 10; ++ks) {
    char* rb = (ks & 1) ? WBb : WBa;
    char* wb = (ks & 1) ? WBa : WBb;
    uint4 st0;
    if (ks < 9) st0 = ((const uint4*)wf1p)[(size_t)(ks + 1) * 256 + tid];
    int arow = w * 16 + l15;
    bf16x8 a = *(const bf16x8*)(A1 + SWZ(arow, arow * 640 + (ks * 32 + lq * 8) * 2));
    #pragma unroll
    for (int nt = 0; nt < 4; ++nt) {
      bf16x8 b = *(const bf16x8*)(rb + (nt * 64 + lane) * 16);
      acc3[nt] = __builtin_amdgcn_mfma_f32_16x16x32_bf16(a, b, acc3[nt], 0, 0, 0);
    }
    if (ks < 9) *(uint4*)(wb + tid * 16) = st0;
    __syncthreads();
  }
  // t = relu(C3+fb1) fp32 [64][52] in A2 region (dead)
  #pragma unroll
  for (int nt = 0; nt < 4; ++nt) {
    int o = nt * 16 + l15;
    if (o < 50) {
      float bias = fb1[o];
      #pragma unroll
      for (int i = 0; i < 4; ++i) {
        int r = w * 16 + lq * 4 + i;
        *(float*)(A2 + r * 208 + o * 4) = frelu(acc3[nt][i] + bias);
      }
    }
  }
  __syncthreads();
  // fp32 tail: 4 threads per edge, 50->25->1
  int el = tid >> 2, q = tid & 3;
  const float* trow = (const float*)(A2 + el * 208);
  float s[7];
  {
    int i = 0;
    #pragma unroll
    for (int j0 = 0; j0 < 25; j0 += 4) { if (j0 + q < 25) s[i++] = b2s[j0 + q]; }
  }
  for (int k = 0; k < 50; ++k) {
    float tv = trow[k];
    int i = 0;
    #pragma unroll
    for (int j0 = 0; j0 < 25; j0 += 4) {
      if (j0 + q < 25) { s[i] = fmaf(tv, W2s[k * 25 + j0 + q], s[i]); ++i; }
    }
  }
  float racc = 0.f;
  {
    int i = 0;
    #pragma unroll
    for (int j0 = 0; j0 < 25; j0 += 4) {
      if (j0 + q < 25) { racc = fmaf(frelu(s[i]), W3s[j0 + q], racc); ++i; }
    }
  }
  racc += __shfl_xor(racc, 1, 4);
  racc += __shfl_xor(racc, 2, 4);
  if (q == 0) out[es[el]] = racc + b3s[0];
}

extern "C" void kernel_launch(void* const* d_in, const int* in_sizes, int n_in,
                              void* d_out, int out_size, void* d_ws, size_t ws_size,
                              hipStream_t stream) {
  (void)in_sizes; (void)n_in; (void)out_size; (void)ws_size;
  const float* x       = (const float*)d_in[0];
  const int*   eidx    = (const int*)  d_in[1];
  const float* eattr   = (const float*)d_in[2];
  const float* node_w  = (const float*)d_in[3];
  const float* node_b  = (const float*)d_in[4];
  const float* edge_w  = (const float*)d_in[5];
  const float* edge_b  = (const float*)d_in[6];
  const float* conv_w1 = (const float*)d_in[7];
  const float* conv_b1 = (const float*)d_in[8];
  const float* conv_w2 = (const float*)d_in[9];
  const float* conv_b2 = (const float*)d_in[10];
  const float* bn_g    = (const float*)d_in[11];
  const float* bn_b    = (const float*)d_in[12];
  const float* em_w1   = (const float*)d_in[13];
  const float* em_b1   = (const float*)d_in[14];
  const float* em_w2   = (const float*)d_in[15];
  const float* em_b2   = (const float*)d_in[16];
  const float* mlp_w1  = (const float*)d_in[17];
  const float* mlp_b1  = (const float*)d_in[18];
  const float* mlp_w2  = (const float*)d_in[19];
  const float* mlp_b2  = (const float*)d_in[20];
  const float* mlp_w3  = (const float*)d_in[21];
  const float* mlp_b3  = (const float*)d_in[22];

  const int* src = eidx;
  const int* dst = eidx + NE;

  // ws layout (max 202.15 MB; ws_size >= 203 MB proven in round 5)
  char* ws = (char*)d_ws;
  float* h    = (float*)(ws);                     // 20,000,000
  float* agg  = (float*)(ws + 20000000);          // 20,000,000
  float* e    = (float*)(ws + 40000000);          // 160,000,000 (PERMUTED rows)
  unsigned short* w1p  = (unsigned short*)(ws + 200000000);  // 71,680
  unsigned short* w2p  = (unsigned short*)(ws + 200071680);  // 28,672
  unsigned short* wf1p = (unsigned short*)(ws + 200100352);  // 40,960
  int* rowptr = (int*)(ws + 200141312);           // 50,001 ints (+pad)
  int* cursor = (int*)(ws + 200341504);           // 50,000 ints
  int* eids   = (int*)(ws + 200541504);           // 400,000 ints
  int* part   = (int*)(ws + 202141504);           // 256 ints

  const int SCAN_NB = (NN + 256) / 256;
  // CSR build (dst-sorted permutation)
  hipMemsetAsync(cursor, 0, (size_t)NN * 4, stream);
  k_hist<<<(NE + 255) / 256, 256, 0, stream>>>(dst, cursor);
  k_scan_part<<<SCAN_NB, 256, 0, stream>>>(cursor, part);
  k_scan_top<<<1, 256, 0, stream>>>(part, SCAN_NB);
  k_scan_fill<<<SCAN_NB, 256, 0, stream>>>(cursor, part, rowptr);
  k_copy<<<SCAN_NB, 256, 0, stream>>>(rowptr, cursor);
  k_fill<<<(NE + 255) / 256, 256, 0, stream>>>(dst, cursor, eids);

  k_node_embed<<<(NN * HD + 255) / 256, 256, 0, stream>>>(x, node_w, node_b, h);
  k_edge_embed_perm<<<((size_t)NE * HD + 255) / 256, 256, 0, stream>>>(eattr, eids, edge_w, edge_b, e);

  k_pack<<<(10 * 4 * 64 + 255) / 256, 256, 0, stream>>>(mlp_w1, wf1p, 300, 50, 10, 4);

  for (int i = 0; i < 2; ++i) {
    k_gather<<<(NN + 63) / 64, 256, 0, stream>>>(h, e, rowptr, eids, src, agg);
    k_node_update<<<(NN + 63) / 64, 256, 0, stream>>>(
        h, agg, conv_w1 + i * HD * HD, conv_b1 + i * HD,
        conv_w2 + i * HD * HD, conv_b2 + i * HD, bn_g + i * HD, bn_b + i * HD);
    k_pack<<<(10 * 7 * 64 + 255) / 256, 256, 0, stream>>>(em_w1 + i * 30000, w1p, 300, 100, 10, 7);
    k_pack<<<(4 * 7 * 64 + 255) / 256, 256, 0, stream>>>(em_w2 + i * 10000,  w2p, 100, 100, 4, 7);
    if (i == 0) {
      k_edge_mfma<<<NE / 64, 256, 0, stream>>>(
          h, e, eids, src, dst, w1p, em_b1, w2p, em_b2);
    } else {
      k_edge_final_mfma<<<NE / 64, 256, 0, stream>>>(
          h, e, eids, src, dst, w1p, em_b1 + HD, w2p, em_b2 + HD,
          wf1p, mlp_b1, mlp_w2, mlp_b2, mlp_w3, mlp_b3, (float*)d_out);
    }
  }
}